// Round 1
// baseline (4934.171 us; speedup 1.0000x reference)
//
#include <hip/hip_runtime.h>
#include <math.h>

#define N_NODES 50000
#define NP      50048          // padded node count (multiple of 64)
#define SEQ     16
#define FIN     64
#define HID     128
#define G3      384
#define NEDGE   1600000
#define NB_SCAN 196            // ceil(50000/256)
#define GRU_KC  24
#define AGG_CAP 96

__device__ __forceinline__ float lrelu02(float v) { return v > 0.f ? v : 0.2f * v; }
__device__ __forceinline__ float sigmoidf_(float v) { return 1.f / (1.f + __expf(-v)); }
__device__ __forceinline__ float eluf_(float v) { return v > 0.f ? v : (__expf(v) - 1.f); }

// ---------------------------------------------------------------------------
// weight prep: transpose once per launch into workspace
//   wTg  [192][384]: k<64 -> w_ih[g][k], else w_hh[g][k-64]
//   g1T/g2T [128][128]: w[g][k] -> [k][g]
// ---------------------------------------------------------------------------
__global__ void prep_weights(const float* __restrict__ w_ih, const float* __restrict__ w_hh,
                             const float* __restrict__ g1w, const float* __restrict__ g2w,
                             float* __restrict__ wTg, float* __restrict__ g1T, float* __restrict__ g2T)
{
    int idx = blockIdx.x * 256 + threadIdx.x;
    if (idx < 192 * 384) {
        int k = idx / 384, g = idx % 384;
        wTg[idx] = (k < 64) ? w_ih[g * 64 + k] : w_hh[g * 128 + (k - 64)];
    }
    int i2 = idx - 192 * 384;
    if (i2 >= 0 && i2 < 128 * 128) {
        int k = i2 >> 7, g = i2 & 127;
        g1T[i2] = g1w[g * 128 + k];
        g2T[i2] = g2w[g * 128 + k];
    }
}

// ---------------------------------------------------------------------------
// GRU step: per block 64 nodes; fused [x_t | h] (K=192) GEMM, 4 phases
// (r: K192, z: K192, i_n: K64, h_n: K128), epilogue does gate math.
// ---------------------------------------------------------------------------
__global__ __launch_bounds__(256) void gru_step_kernel(
    const float* __restrict__ x,     // [N, 16, 64]
    const float* __restrict__ wT,    // [192][384]
    const float* __restrict__ b_ih,  // [384]
    const float* __restrict__ b_hh,  // [384]
    float* __restrict__ h,           // [NP][128] in/out
    int t)
{
    __shared__ float in_tile[64][193];       // [node][k]  k<64: x_t, k>=64: h
    __shared__ float w_tile[GRU_KC][128];

    const int tid = threadIdx.x;
    const int tx = tid & 15;     // node group (4 nodes each)
    const int ty = tid >> 4;     // output group (8 outs each)
    const int n0 = blockIdx.x * 64;

    // stage x_t (64 nodes x 64 feats), coalesced, contiguous LDS rows
#pragma unroll
    for (int i = 0; i < 16; i++) {
        int flat = tid + i * 256;
        int n = flat >> 6, f = flat & 63;
        int gn = n0 + n; if (gn > N_NODES - 1) gn = N_NODES - 1;
        in_tile[n][f] = x[(gn * SEQ + t) * FIN + f];
    }
    // stage h (64 x 128)
#pragma unroll
    for (int i = 0; i < 32; i++) {
        int flat = tid + i * 256;
        int n = flat >> 7, c = flat & 127;
        in_tile[n][64 + c] = h[(n0 + n) * HID + c];
    }

    float r_[4][8], z_[4][8], in_[4][8], acc[4][8];

    auto kbody = [&](int kk, int k) {
        float xv[4];
#pragma unroll
        for (int i = 0; i < 4; i++) xv[i] = in_tile[tx * 4 + i][k];
        float4 wa = *(const float4*)&w_tile[kk][ty * 8];
        float4 wb = *(const float4*)&w_tile[kk][ty * 8 + 4];
        float wv[8] = {wa.x, wa.y, wa.z, wa.w, wb.x, wb.y, wb.z, wb.w};
#pragma unroll
        for (int i = 0; i < 4; i++)
#pragma unroll
            for (int j = 0; j < 8; j++)
                acc[i][j] = fmaf(xv[i], wv[j], acc[i][j]);
    };

    auto run_phase = [&](int ks, int ke, int gb) {
#pragma unroll
        for (int i = 0; i < 4; i++)
#pragma unroll
            for (int j = 0; j < 8; j++) acc[i][j] = 0.f;
        for (int k0 = ks; k0 < ke; k0 += GRU_KC) {
            int kl = ke - k0; if (kl > GRU_KC) kl = GRU_KC;
            __syncthreads();   // protect w_tile from previous readers / in_tile staging
#pragma unroll
            for (int i = 0; i < 12; i++) {
                int flat = tid + i * 256;
                int kk = flat >> 7, g = flat & 127;
                if (kk < kl) w_tile[kk][g] = wT[(k0 + kk) * G3 + gb + g];
            }
            __syncthreads();
            if (kl == GRU_KC) {
#pragma unroll 4
                for (int kk = 0; kk < GRU_KC; kk++) kbody(kk, k0 + kk);
            } else {
                for (int kk = 0; kk < kl; kk++) kbody(kk, k0 + kk);
            }
        }
    };

    // r gate: rows [0,128), K = 192
    run_phase(0, 192, 0);
    {
        float4 ba = *(const float4*)&b_ih[ty * 8];
        float4 bb = *(const float4*)&b_ih[ty * 8 + 4];
        float4 ca = *(const float4*)&b_hh[ty * 8];
        float4 cb = *(const float4*)&b_hh[ty * 8 + 4];
        float bias[8] = {ba.x + ca.x, ba.y + ca.y, ba.z + ca.z, ba.w + ca.w,
                         bb.x + cb.x, bb.y + cb.y, bb.z + cb.z, bb.w + cb.w};
#pragma unroll
        for (int i = 0; i < 4; i++)
#pragma unroll
            for (int j = 0; j < 8; j++) r_[i][j] = sigmoidf_(acc[i][j] + bias[j]);
    }
    // z gate: rows [128,256), K = 192
    run_phase(0, 192, 128);
    {
        float4 ba = *(const float4*)&b_ih[128 + ty * 8];
        float4 bb = *(const float4*)&b_ih[128 + ty * 8 + 4];
        float4 ca = *(const float4*)&b_hh[128 + ty * 8];
        float4 cb = *(const float4*)&b_hh[128 + ty * 8 + 4];
        float bias[8] = {ba.x + ca.x, ba.y + ca.y, ba.z + ca.z, ba.w + ca.w,
                         bb.x + cb.x, bb.y + cb.y, bb.z + cb.z, bb.w + cb.w};
#pragma unroll
        for (int i = 0; i < 4; i++)
#pragma unroll
            for (int j = 0; j < 8; j++) z_[i][j] = sigmoidf_(acc[i][j] + bias[j]);
    }
    // i_n: rows [256,384), K = 64 (x part only)
    run_phase(0, 64, 256);
    {
        float4 ba = *(const float4*)&b_ih[256 + ty * 8];
        float4 bb = *(const float4*)&b_ih[256 + ty * 8 + 4];
        float bias[8] = {ba.x, ba.y, ba.z, ba.w, bb.x, bb.y, bb.z, bb.w};
#pragma unroll
        for (int i = 0; i < 4; i++)
#pragma unroll
            for (int j = 0; j < 8; j++) in_[i][j] = acc[i][j] + bias[j];
    }
    // h_n: rows [256,384), K = 128 (h part only)
    run_phase(64, 192, 256);
    {
        float4 ca = *(const float4*)&b_hh[256 + ty * 8];
        float4 cb = *(const float4*)&b_hh[256 + ty * 8 + 4];
        float bhn[8] = {ca.x, ca.y, ca.z, ca.w, cb.x, cb.y, cb.z, cb.w};
#pragma unroll
        for (int i = 0; i < 4; i++) {
            float o[8];
#pragma unroll
            for (int j = 0; j < 8; j++) {
                float hn = acc[i][j] + bhn[j];
                float nn = tanhf(in_[i][j] + r_[i][j] * hn);
                float ho = in_tile[tx * 4 + i][64 + ty * 8 + j];
                o[j] = (1.f - z_[i][j]) * nn + z_[i][j] * ho;
            }
            float* hp = &h[(n0 + tx * 4 + i) * HID + ty * 8];
            *(float4*)&hp[0] = make_float4(o[0], o[1], o[2], o[3]);
            *(float4*)&hp[4] = make_float4(o[4], o[5], o[6], o[7]);
        }
    }
}

// ---------------------------------------------------------------------------
// CSR build
// ---------------------------------------------------------------------------
__global__ void count_edges(const int* __restrict__ dst, int* __restrict__ deg, int e)
{
    int i = blockIdx.x * 256 + threadIdx.x;
    if (i < e) atomicAdd(&deg[dst[i]], 1);
}

__device__ __forceinline__ int block_scan_inc(int v)
{
    int tid = threadIdx.x, lane = tid & 63, w = tid >> 6;
#pragma unroll
    for (int off = 1; off < 64; off <<= 1) {
        int tmp = __shfl_up(v, off, 64);
        if (lane >= off) v += tmp;
    }
    __shared__ int wsum[4];
    if (lane == 63) wsum[w] = v;
    __syncthreads();
    int add = 0;
    for (int i = 0; i < w; i++) add += wsum[i];
    return v + add;
}

__global__ void scan_block_sums(const int* __restrict__ deg, int* __restrict__ bsum, int n)
{
    int i = blockIdx.x * 256 + threadIdx.x;
    int v = (i < n) ? deg[i] : 0;
#pragma unroll
    for (int off = 32; off >= 1; off >>= 1) v += __shfl_xor(v, off, 64);
    __shared__ int ws[4];
    if ((threadIdx.x & 63) == 0) ws[threadIdx.x >> 6] = v;
    __syncthreads();
    if (threadIdx.x == 0) bsum[blockIdx.x] = ws[0] + ws[1] + ws[2] + ws[3];
}

__global__ void scan_bsum(int* __restrict__ bsum, int nb)
{
    int tid = threadIdx.x;
    int v = (tid < nb) ? bsum[tid] : 0;
    v = block_scan_inc(v);
    if (tid < nb) bsum[tid] = v;
}

__global__ void scan_final(const int* __restrict__ deg, const int* __restrict__ bsum,
                           int* __restrict__ rp, int n)
{
    int i = blockIdx.x * 256 + threadIdx.x;
    int v = (i < n) ? deg[i] : 0;
    int s = block_scan_inc(v);
    int add = (blockIdx.x > 0) ? bsum[blockIdx.x - 1] : 0;
    if (i < n) rp[i + 1] = s + add;
    if (i == 0) rp[0] = 0;
}

__global__ void fill_edges(const int* __restrict__ src, const int* __restrict__ dst,
                           const int* __restrict__ rp, int* __restrict__ cur,
                           int* __restrict__ col, int e)
{
    int i = blockIdx.x * 256 + threadIdx.x;
    if (i < e) {
        int d = dst[i];
        int pos = atomicAdd(&cur[d], 1);
        col[rp[d] + pos] = src[i];
    }
}

// ---------------------------------------------------------------------------
// GAT projection: hp = x @ wT  (128x128), 32 nodes/block
// ---------------------------------------------------------------------------
__global__ __launch_bounds__(256) void gemm_proj(
    const float* __restrict__ x, const float* __restrict__ wT, float* __restrict__ hp)
{
    __shared__ float xt[32][129];
    __shared__ float wt[32][128];
    const int tid = threadIdx.x;
    const int tx = tid & 7;       // 8 node groups of 4
    const int ty = tid >> 3;      // 32 out groups of 4
    const int n0 = blockIdx.x * 32;
    float acc[4][4];
#pragma unroll
    for (int i = 0; i < 4; i++)
#pragma unroll
        for (int j = 0; j < 4; j++) acc[i][j] = 0.f;

    for (int k0 = 0; k0 < 128; k0 += 32) {
        __syncthreads();
#pragma unroll
        for (int i = 0; i < 4; i++) {
            int flat = tid + i * 256;
            int n = flat >> 5, k = flat & 31;
            xt[n][k] = x[(n0 + n) * HID + k0 + k];
        }
#pragma unroll
        for (int i = 0; i < 16; i++) {
            int flat = tid + i * 256;
            int kk = flat >> 7, g = flat & 127;
            wt[kk][g] = wT[(k0 + kk) * HID + g];
        }
        __syncthreads();
#pragma unroll 8
        for (int kk = 0; kk < 32; kk++) {
            float xv[4];
#pragma unroll
            for (int i = 0; i < 4; i++) xv[i] = xt[tx * 4 + i][kk];
            float4 wv = *(const float4*)&wt[kk][ty * 4];
#pragma unroll
            for (int i = 0; i < 4; i++) {
                acc[i][0] = fmaf(xv[i], wv.x, acc[i][0]);
                acc[i][1] = fmaf(xv[i], wv.y, acc[i][1]);
                acc[i][2] = fmaf(xv[i], wv.z, acc[i][2]);
                acc[i][3] = fmaf(xv[i], wv.w, acc[i][3]);
            }
        }
    }
#pragma unroll
    for (int i = 0; i < 4; i++)
        *(float4*)&hp[(n0 + tx * 4 + i) * HID + ty * 4] =
            make_float4(acc[i][0], acc[i][1], acc[i][2], acc[i][3]);
}

// ---------------------------------------------------------------------------
// attention coefficients: a_s[n,h] = <hp[n, h*32:], a_src[h]>, same for a_d
// ---------------------------------------------------------------------------
__global__ void attn_coef(const float* __restrict__ hp, const float* __restrict__ a_src,
                          const float* __restrict__ a_dst,
                          float* __restrict__ as_, float* __restrict__ ad_, int n)
{
    int idx = blockIdx.x * 256 + threadIdx.x;
    if (idx >= n * 4) return;
    int node = idx >> 2, hh = idx & 3;
    const float* hr = hp + node * HID + hh * 32;
    const float* ar = a_src + hh * 32;
    const float* br = a_dst + hh * 32;
    float s = 0.f, d = 0.f;
#pragma unroll
    for (int j = 0; j < 32; j += 4) {
        float4 hv = *(const float4*)&hr[j];
        float4 av = *(const float4*)&ar[j];
        float4 bv = *(const float4*)&br[j];
        s += hv.x * av.x + hv.y * av.y + hv.z * av.z + hv.w * av.w;
        d += hv.x * bv.x + hv.y * bv.y + hv.z * bv.z + hv.w * bv.w;
    }
    as_[idx] = s;
    ad_[idx] = d;
}

// ---------------------------------------------------------------------------
// GAT aggregation: one wave per dst node. CSR edges + implicit self-loop.
// lane owns channels lane and lane+64. Output = elu(sum + bias).
// ---------------------------------------------------------------------------
__global__ __launch_bounds__(256) void gat_agg(
    const float* __restrict__ hp, const float* __restrict__ as_,
    const float* __restrict__ ad_, const int* __restrict__ rp,
    const int* __restrict__ col, const float* __restrict__ bias,
    float* __restrict__ out, int n_nodes)
{
    __shared__ float exl[4][AGG_CAP][4];
    const int widx = threadIdx.x >> 6;
    const int lane = threadIdx.x & 63;
    const int n = blockIdx.x * 4 + widx;
    if (n >= n_nodes) return;

    const int e0 = rp[n], e1 = rp[n + 1];
    float4 adv = *(const float4*)&ad_[n * 4];
    float4 asn = *(const float4*)&as_[n * 4];
    // self-loop logit
    float es0 = lrelu02(asn.x + adv.x), es1 = lrelu02(asn.y + adv.y);
    float es2 = lrelu02(asn.z + adv.z), es3 = lrelu02(asn.w + adv.w);

    // phase 1: max
    float m0 = es0, m1 = es1, m2 = es2, m3 = es3;
    for (int e = e0 + lane; e < e1; e += 64) {
        int s = col[e];
        float4 a = *(const float4*)&as_[s * 4];
        m0 = fmaxf(m0, lrelu02(a.x + adv.x));
        m1 = fmaxf(m1, lrelu02(a.y + adv.y));
        m2 = fmaxf(m2, lrelu02(a.z + adv.z));
        m3 = fmaxf(m3, lrelu02(a.w + adv.w));
    }
#pragma unroll
    for (int off = 32; off >= 1; off >>= 1) {
        m0 = fmaxf(m0, __shfl_xor(m0, off, 64));
        m1 = fmaxf(m1, __shfl_xor(m1, off, 64));
        m2 = fmaxf(m2, __shfl_xor(m2, off, 64));
        m3 = fmaxf(m3, __shfl_xor(m3, off, 64));
    }

    // phase 2: exp + denom; cache exp in LDS
    float d0 = 0.f, d1 = 0.f, d2 = 0.f, d3 = 0.f;
    for (int e = e0 + lane; e < e1; e += 64) {
        int s = col[e];
        float4 a = *(const float4*)&as_[s * 4];
        float x0 = __expf(lrelu02(a.x + adv.x) - m0);
        float x1 = __expf(lrelu02(a.y + adv.y) - m1);
        float x2 = __expf(lrelu02(a.z + adv.z) - m2);
        float x3 = __expf(lrelu02(a.w + adv.w) - m3);
        int idx = e - e0;
        if (idx < AGG_CAP) {
            exl[widx][idx][0] = x0; exl[widx][idx][1] = x1;
            exl[widx][idx][2] = x2; exl[widx][idx][3] = x3;
        }
        d0 += x0; d1 += x1; d2 += x2; d3 += x3;
    }
#pragma unroll
    for (int off = 32; off >= 1; off >>= 1) {
        d0 += __shfl_xor(d0, off, 64);
        d1 += __shfl_xor(d1, off, 64);
        d2 += __shfl_xor(d2, off, 64);
        d3 += __shfl_xor(d3, off, 64);
    }
    float xs0 = __expf(es0 - m0), xs1 = __expf(es1 - m1);
    float xs2 = __expf(es2 - m2), xs3 = __expf(es3 - m3);
    d0 += xs0; d1 += xs1; d2 += xs2; d3 += xs3;
    float i0 = 1.f / (d0 + 1e-16f), i1 = 1.f / (d1 + 1e-16f);
    float i2 = 1.f / (d2 + 1e-16f), i3 = 1.f / (d3 + 1e-16f);

    // phase 3: weighted accumulation. channel c0 = lane, c1 = lane + 64
    const bool hi = lane >= 32;
    const int c0 = lane, c1 = lane + 64;
    float inv0 = hi ? i1 : i0, inv1 = hi ? i3 : i2;
    float mm0 = hi ? m1 : m0, mm1 = hi ? m3 : m2;
    float ad0 = hi ? adv.y : adv.x, ad1 = hi ? adv.w : adv.z;
    float ex_s0 = hi ? xs1 : xs0, ex_s1 = hi ? xs3 : xs2;

    float acc0 = ex_s0 * inv0 * hp[n * HID + c0];
    float acc1 = ex_s1 * inv1 * hp[n * HID + c1];
    for (int e = e0; e < e1; e++) {
        int s = col[e];
        int idx = e - e0;
        float e_c0, e_c1;
        if (idx < AGG_CAP) {
            e_c0 = exl[widx][idx][hi ? 1 : 0];
            e_c1 = exl[widx][idx][hi ? 3 : 2];
        } else {
            float4 a = *(const float4*)&as_[s * 4];
            e_c0 = __expf(lrelu02((hi ? a.y : a.x) + ad0) - mm0);
            e_c1 = __expf(lrelu02((hi ? a.w : a.z) + ad1) - mm1);
        }
        acc0 = fmaf(e_c0 * inv0, hp[s * HID + c0], acc0);
        acc1 = fmaf(e_c1 * inv1, hp[s * HID + c1], acc1);
    }
    out[n * HID + c0] = eluf_(acc0 + bias[c0]);
    out[n * HID + c1] = eluf_(acc1 + bias[c1]);
}

// ---------------------------------------------------------------------------
// classifier: out[n] = sigmoid(<x[n], w> + b), one wave per node
// ---------------------------------------------------------------------------
__global__ void classifier_kernel(const float* __restrict__ x, const float* __restrict__ w,
                                  const float* __restrict__ b, float* __restrict__ out, int n)
{
    int wv = (blockIdx.x * 256 + threadIdx.x) >> 6;
    int lane = threadIdx.x & 63;
    if (wv >= n) return;
    float acc = x[wv * HID + lane] * w[lane] + x[wv * HID + 64 + lane] * w[64 + lane];
#pragma unroll
    for (int off = 32; off >= 1; off >>= 1) acc += __shfl_xor(acc, off, 64);
    if (lane == 0) out[wv] = sigmoidf_(acc + b[0]);
}

// ---------------------------------------------------------------------------
extern "C" void kernel_launch(void* const* d_in, const int* in_sizes, int n_in,
                              void* d_out, int out_size, void* d_ws, size_t ws_size,
                              hipStream_t stream)
{
    const float* x     = (const float*)d_in[0];
    const int*   ei    = (const int*)d_in[1];
    const float* w_ih  = (const float*)d_in[2];
    const float* w_hh  = (const float*)d_in[3];
    const float* b_ih  = (const float*)d_in[4];
    const float* b_hh  = (const float*)d_in[5];
    const float* g1w   = (const float*)d_in[6];
    const float* g1as  = (const float*)d_in[7];
    const float* g1ad  = (const float*)d_in[8];
    const float* g1b   = (const float*)d_in[9];
    const float* g2w   = (const float*)d_in[10];
    const float* g2as  = (const float*)d_in[11];
    const float* g2ad  = (const float*)d_in[12];
    const float* g2b   = (const float*)d_in[13];
    const float* cw    = (const float*)d_in[14];
    const float* cb    = (const float*)d_in[15];
    float* out = (float*)d_out;

    char* wsb = (char*)d_ws;
    size_t off = 0;
    auto alc = [&](size_t bytes) { size_t o = off; off += (bytes + 255) & ~(size_t)255; return o; };

    float* bufA = (float*)(wsb + alc((size_t)NP * HID * 4));
    float* bufB = (float*)(wsb + alc((size_t)NP * HID * 4));
    float* bufC = (float*)(wsb + alc((size_t)NP * HID * 4));
    float* as_  = (float*)(wsb + alc((size_t)NP * 4 * 4));
    float* ad_  = (float*)(wsb + alc((size_t)NP * 4 * 4));
    float* wTg  = (float*)(wsb + alc((size_t)192 * 384 * 4));
    float* g1T  = (float*)(wsb + alc((size_t)128 * 128 * 4));
    float* g2T  = (float*)(wsb + alc((size_t)128 * 128 * 4));
    int*   rp   = (int*)(wsb + alc((size_t)(N_NODES + 1) * 4));
    int*   deg  = (int*)(wsb + alc((size_t)N_NODES * 4));
    int*   cur  = (int*)(wsb + alc((size_t)N_NODES * 4));
    int*   col  = (int*)(wsb + alc((size_t)NEDGE * 4));
    int*   bsum = (int*)(wsb + alc((size_t)256 * 4));

    const int* src = ei;
    const int* dst = ei + NEDGE;

    hipMemsetAsync(bufA, 0, (size_t)NP * HID * 4, stream);   // h0 = 0
    hipMemsetAsync(deg, 0, (size_t)N_NODES * 4, stream);
    hipMemsetAsync(cur, 0, (size_t)N_NODES * 4, stream);

    prep_weights<<<352, 256, 0, stream>>>(w_ih, w_hh, g1w, g2w, wTg, g1T, g2T);

    // CSR build (reused by both GAT layers)
    count_edges<<<NEDGE / 256, 256, 0, stream>>>(dst, deg, NEDGE);
    scan_block_sums<<<NB_SCAN, 256, 0, stream>>>(deg, bsum, N_NODES);
    scan_bsum<<<1, 256, 0, stream>>>(bsum, NB_SCAN);
    scan_final<<<NB_SCAN, 256, 0, stream>>>(deg, bsum, rp, N_NODES);
    fill_edges<<<NEDGE / 256, 256, 0, stream>>>(src, dst, rp, cur, col, NEDGE);

    // GRU: 16 sequential steps, h in bufA
    for (int t = 0; t < SEQ; t++)
        gru_step_kernel<<<NP / 64, 256, 0, stream>>>(x, wTg, b_ih, b_hh, bufA, t);

    // GAT layer 1: bufA -> bufB (proj) -> bufC (agg+elu)
    gemm_proj<<<NP / 32, 256, 0, stream>>>(bufA, g1T, bufB);
    attn_coef<<<(N_NODES * 4 + 255) / 256, 256, 0, stream>>>(bufB, g1as, g1ad, as_, ad_, N_NODES);
    gat_agg<<<(N_NODES + 3) / 4, 256, 0, stream>>>(bufB, as_, ad_, rp, col, g1b, bufC, N_NODES);

    // GAT layer 2: bufC -> bufB (proj) -> bufA (agg+elu)
    gemm_proj<<<NP / 32, 256, 0, stream>>>(bufC, g2T, bufB);
    attn_coef<<<(N_NODES * 4 + 255) / 256, 256, 0, stream>>>(bufB, g2as, g2ad, as_, ad_, N_NODES);
    gat_agg<<<(N_NODES + 3) / 4, 256, 0, stream>>>(bufB, as_, ad_, rp, col, g2b, bufA, N_NODES);

    // classifier
    classifier_kernel<<<(N_NODES + 3) / 4, 256, 0, stream>>>(bufA, cw, cb, out, N_NODES);
}

// Round 2
// 1437.108 us; speedup vs baseline: 3.4334x; 3.4334x over previous
//
#include <hip/hip_runtime.h>
#include <math.h>

#define N_NODES 50000
#define NP      50048          // padded node count (multiple of 64)
#define SEQ     16
#define FIN     64
#define HID     128
#define G3      384
#define NEDGE   1600000
#define NB_SCAN 196            // ceil(50000/256)
#define AGG_CAP 96

typedef __attribute__((ext_vector_type(8))) short short8;   // 8 bf16 = 4 VGPRs
typedef __attribute__((ext_vector_type(4))) float f32x4;

__device__ __forceinline__ float lrelu02(float v) { return v > 0.f ? v : 0.2f * v; }
__device__ __forceinline__ float frcp(float v) { return __builtin_amdgcn_rcpf(v); }
__device__ __forceinline__ float sigmoidf_(float v) { return frcp(1.f + __expf(-v)); }
__device__ __forceinline__ float eluf_(float v) { return v > 0.f ? v : (__expf(v) - 1.f); }

__device__ __forceinline__ short f2bf(float f) {
    unsigned u = __builtin_bit_cast(unsigned, f);
    u = (u + 0x7FFF + ((u >> 16) & 1)) >> 16;   // RNE
    return (short)u;
}
__device__ __forceinline__ short8 pack8(float4 a, float4 b) {
    short8 r;
    r[0] = f2bf(a.x); r[1] = f2bf(a.y); r[2] = f2bf(a.z); r[3] = f2bf(a.w);
    r[4] = f2bf(b.x); r[5] = f2bf(b.y); r[6] = f2bf(b.z); r[7] = f2bf(b.w);
    return r;
}

// ---------------------------------------------------------------------------
// Fused GRU: one block = 32 nodes, all 16 timesteps. 512 threads = 8 waves.
// Wave w owns output cols [48w, 48w+48) of the 384 gate outputs.
// Weights resident in VGPR B-fragments for the whole kernel.
// MFMA 16x16x32 bf16: A[m=lane&15][k=(lane>>4)*8+j], B[n=lane&15][k=...],
// C/D col=lane&15, row=(lane>>4)*4+reg.
// ---------------------------------------------------------------------------
__global__ __launch_bounds__(512) void gru_fused(
    const float* __restrict__ x,     // [N][16][64]
    const float* __restrict__ w_ih,  // [384][64]
    const float* __restrict__ w_hh,  // [384][128]
    const float* __restrict__ b_ih,  // [384]
    const float* __restrict__ b_hh,  // [384]
    float* __restrict__ hout)        // [NP][128]
{
    __shared__ float S1[32][130];    // i_r + h_r
    __shared__ float S2[32][130];    // i_z + h_z
    __shared__ float inA[32][130];   // i_n
    __shared__ float hnA[32][130];   // h_n
    __shared__ __align__(16) short hA[32][136];  // h as bf16, A-frag layout

    const int tid  = threadIdx.x;
    const int wave = tid >> 6;
    const int lane = tid & 63;
    const int q    = lane >> 4;      // quad 0..3
    const int rl   = lane & 15;
    const int n0   = blockIdx.x * 32;
    const int colbase = wave * 48;

    // ---- load resident weight B-fragments (bf16) ----
    short8 whhf[3][4];   // [nt][kc]  K=128
    short8 wihf[3][2];   // [nt][kc]  K=64
#pragma unroll
    for (int nt = 0; nt < 3; nt++) {
        int g = colbase + nt * 16 + rl;
#pragma unroll
        for (int kc = 0; kc < 4; kc++) {
            const float* p = w_hh + g * HID + kc * 32 + q * 8;
            whhf[nt][kc] = pack8(*(const float4*)p, *(const float4*)(p + 4));
        }
#pragma unroll
        for (int kc = 0; kc < 2; kc++) {
            const float* p = w_ih + g * FIN + kc * 32 + q * 8;
            wihf[nt][kc] = pack8(*(const float4*)p, *(const float4*)(p + 4));
        }
    }

    // ---- per-thread gate-math assignment: 1 channel x 8 nodes ----
    const int ch = tid & 127;
    const int ng = tid >> 7;         // node group 0..3 (8 nodes each)
    float br  = b_ih[ch] + b_hh[ch];
    float bz  = b_ih[128 + ch] + b_hh[128 + ch];
    float bin = b_ih[256 + ch];
    float bhn = b_hh[256 + ch];
    float hreg[8];
#pragma unroll
    for (int i = 0; i < 8; i++) hreg[i] = 0.f;

    for (int t = 0; t < SEQ; t++) {
        f32x4 accx[2][3], acch[2][3];
#pragma unroll
        for (int mt = 0; mt < 2; mt++)
#pragma unroll
            for (int nt = 0; nt < 3; nt++) {
                accx[mt][nt] = (f32x4)0.f;
                acch[mt][nt] = (f32x4)0.f;
            }

        // A-fragments: H from LDS (prev step), X from global
        short8 hf[2][4], xf[2][2];
        if (t > 0) {
#pragma unroll
            for (int mt = 0; mt < 2; mt++)
#pragma unroll
                for (int kc = 0; kc < 4; kc++)
                    hf[mt][kc] = *(const short8*)&hA[mt * 16 + rl][kc * 32 + q * 8];
        }
#pragma unroll
        for (int mt = 0; mt < 2; mt++) {
            int gn = n0 + mt * 16 + rl;
            if (gn > N_NODES - 1) gn = N_NODES - 1;
            const float* xp = x + ((size_t)gn * SEQ + t) * FIN + q * 8;
#pragma unroll
            for (int kc = 0; kc < 2; kc++)
                xf[mt][kc] = pack8(*(const float4*)(xp + kc * 32),
                                   *(const float4*)(xp + kc * 32 + 4));
        }

        // MFMAs
#pragma unroll
        for (int mt = 0; mt < 2; mt++)
#pragma unroll
            for (int nt = 0; nt < 3; nt++) {
#pragma unroll
                for (int kc = 0; kc < 2; kc++)
                    accx[mt][nt] = __builtin_amdgcn_mfma_f32_16x16x32_bf16(
                        xf[mt][kc], wihf[nt][kc], accx[mt][nt], 0, 0, 0);
                if (t > 0) {
#pragma unroll
                    for (int kc = 0; kc < 4; kc++)
                        acch[mt][nt] = __builtin_amdgcn_mfma_f32_16x16x32_bf16(
                            hf[mt][kc], whhf[nt][kc], acch[mt][nt], 0, 0, 0);
                }
            }

        // scatter C-tiles to LDS
#pragma unroll
        for (int mt = 0; mt < 2; mt++)
#pragma unroll
            for (int nt = 0; nt < 3; nt++) {
                int c = colbase + nt * 16 + rl;   // wave-uniform gate per tile
#pragma unroll
                for (int reg = 0; reg < 4; reg++) {
                    int node = mt * 16 + q * 4 + reg;
                    float gx = accx[mt][nt][reg];
                    float gh = acch[mt][nt][reg];
                    if (c < 128)       S1[node][c] = gx + gh;
                    else if (c < 256)  S2[node][c - 128] = gx + gh;
                    else { inA[node][c - 256] = gx; hnA[node][c - 256] = gh; }
                }
            }
        __syncthreads();

        // gate math: h fp32 in registers, bf16 copy to hA for next step
#pragma unroll
        for (int i = 0; i < 8; i++) {
            int node = ng * 8 + i;
            float s1 = S1[node][ch], s2 = S2[node][ch];
            float gin = inA[node][ch], ghn = hnA[node][ch];
            float r = sigmoidf_(s1 + br);
            float z = sigmoidf_(s2 + bz);
            float a = gin + bin + r * (ghn + bhn);
            float e = __expf(2.f * a);
            float nn = 1.f - 2.f * frcp(e + 1.f);
            hreg[i] = (1.f - z) * nn + z * hreg[i];
            hA[node][ch] = f2bf(hreg[i]);
        }
        __syncthreads();
    }

    // final h to global (fp32)
#pragma unroll
    for (int i = 0; i < 8; i++)
        hout[(size_t)(n0 + ng * 8 + i) * HID + ch] = hreg[i];
}

// ---------------------------------------------------------------------------
// weight prep for GAT projections: w[g][k] -> [k][g]
// ---------------------------------------------------------------------------
__global__ void prep_weights(const float* __restrict__ g1w, const float* __restrict__ g2w,
                             float* __restrict__ g1T, float* __restrict__ g2T)
{
    int i = blockIdx.x * 256 + threadIdx.x;
    if (i < 128 * 128) {
        int k = i >> 7, g = i & 127;
        g1T[i] = g1w[g * 128 + k];
        g2T[i] = g2w[g * 128 + k];
    }
}

// ---------------------------------------------------------------------------
// CSR build
// ---------------------------------------------------------------------------
__global__ void count_edges(const int* __restrict__ dst, int* __restrict__ deg, int e)
{
    int i = blockIdx.x * 256 + threadIdx.x;
    if (i < e) atomicAdd(&deg[dst[i]], 1);
}

__device__ __forceinline__ int block_scan_inc(int v)
{
    int tid = threadIdx.x, lane = tid & 63, w = tid >> 6;
#pragma unroll
    for (int off = 1; off < 64; off <<= 1) {
        int tmp = __shfl_up(v, off, 64);
        if (lane >= off) v += tmp;
    }
    __shared__ int wsum[4];
    if (lane == 63) wsum[w] = v;
    __syncthreads();
    int add = 0;
    for (int i = 0; i < w; i++) add += wsum[i];
    return v + add;
}

__global__ void scan_block_sums(const int* __restrict__ deg, int* __restrict__ bsum, int n)
{
    int i = blockIdx.x * 256 + threadIdx.x;
    int v = (i < n) ? deg[i] : 0;
#pragma unroll
    for (int off = 32; off >= 1; off >>= 1) v += __shfl_xor(v, off, 64);
    __shared__ int ws[4];
    if ((threadIdx.x & 63) == 0) ws[threadIdx.x >> 6] = v;
    __syncthreads();
    if (threadIdx.x == 0) bsum[blockIdx.x] = ws[0] + ws[1] + ws[2] + ws[3];
}

__global__ void scan_bsum(int* __restrict__ bsum, int nb)
{
    int tid = threadIdx.x;
    int v = (tid < nb) ? bsum[tid] : 0;
    v = block_scan_inc(v);
    if (tid < nb) bsum[tid] = v;
}

__global__ void scan_final(const int* __restrict__ deg, const int* __restrict__ bsum,
                           int* __restrict__ rp, int n)
{
    int i = blockIdx.x * 256 + threadIdx.x;
    int v = (i < n) ? deg[i] : 0;
    int s = block_scan_inc(v);
    int add = (blockIdx.x > 0) ? bsum[blockIdx.x - 1] : 0;
    if (i < n) rp[i + 1] = s + add;
    if (i == 0) rp[0] = 0;
}

__global__ void fill_edges(const int* __restrict__ src, const int* __restrict__ dst,
                           const int* __restrict__ rp, int* __restrict__ cur,
                           int* __restrict__ col, int e)
{
    int i = blockIdx.x * 256 + threadIdx.x;
    if (i < e) {
        int d = dst[i];
        int pos = atomicAdd(&cur[d], 1);
        col[rp[d] + pos] = src[i];
    }
}

// ---------------------------------------------------------------------------
// GAT projection: hp = x @ wT  (128x128), 32 nodes/block
// ---------------------------------------------------------------------------
__global__ __launch_bounds__(256) void gemm_proj(
    const float* __restrict__ x, const float* __restrict__ wT, float* __restrict__ hp)
{
    __shared__ float xt[32][129];
    __shared__ float wt[32][128];
    const int tid = threadIdx.x;
    const int tx = tid & 7;       // 8 node groups of 4
    const int ty = tid >> 3;      // 32 out groups of 4
    const int n0 = blockIdx.x * 32;
    float acc[4][4];
#pragma unroll
    for (int i = 0; i < 4; i++)
#pragma unroll
        for (int j = 0; j < 4; j++) acc[i][j] = 0.f;

    for (int k0 = 0; k0 < 128; k0 += 32) {
        __syncthreads();
#pragma unroll
        for (int i = 0; i < 4; i++) {
            int flat = tid + i * 256;
            int n = flat >> 5, k = flat & 31;
            xt[n][k] = x[(n0 + n) * HID + k0 + k];
        }
#pragma unroll
        for (int i = 0; i < 16; i++) {
            int flat = tid + i * 256;
            int kk = flat >> 7, g = flat & 127;
            wt[kk][g] = wT[(k0 + kk) * HID + g];
        }
        __syncthreads();
#pragma unroll 8
        for (int kk = 0; kk < 32; kk++) {
            float xv[4];
#pragma unroll
            for (int i = 0; i < 4; i++) xv[i] = xt[tx * 4 + i][kk];
            float4 wv = *(const float4*)&wt[kk][ty * 4];
#pragma unroll
            for (int i = 0; i < 4; i++) {
                acc[i][0] = fmaf(xv[i], wv.x, acc[i][0]);
                acc[i][1] = fmaf(xv[i], wv.y, acc[i][1]);
                acc[i][2] = fmaf(xv[i], wv.z, acc[i][2]);
                acc[i][3] = fmaf(xv[i], wv.w, acc[i][3]);
            }
        }
    }
#pragma unroll
    for (int i = 0; i < 4; i++)
        *(float4*)&hp[(n0 + tx * 4 + i) * HID + ty * 4] =
            make_float4(acc[i][0], acc[i][1], acc[i][2], acc[i][3]);
}

// ---------------------------------------------------------------------------
// attention coefficients
// ---------------------------------------------------------------------------
__global__ void attn_coef(const float* __restrict__ hp, const float* __restrict__ a_src,
                          const float* __restrict__ a_dst,
                          float* __restrict__ as_, float* __restrict__ ad_, int n)
{
    int idx = blockIdx.x * 256 + threadIdx.x;
    if (idx >= n * 4) return;
    int node = idx >> 2, hh = idx & 3;
    const float* hr = hp + node * HID + hh * 32;
    const float* ar = a_src + hh * 32;
    const float* br = a_dst + hh * 32;
    float s = 0.f, d = 0.f;
#pragma unroll
    for (int j = 0; j < 32; j += 4) {
        float4 hv = *(const float4*)&hr[j];
        float4 av = *(const float4*)&ar[j];
        float4 bv = *(const float4*)&br[j];
        s += hv.x * av.x + hv.y * av.y + hv.z * av.z + hv.w * av.w;
        d += hv.x * bv.x + hv.y * bv.y + hv.z * bv.z + hv.w * bv.w;
    }
    as_[idx] = s;
    ad_[idx] = d;
}

// ---------------------------------------------------------------------------
// GAT aggregation: one wave per dst node, CSR + implicit self-loop
// ---------------------------------------------------------------------------
__global__ __launch_bounds__(256) void gat_agg(
    const float* __restrict__ hp, const float* __restrict__ as_,
    const float* __restrict__ ad_, const int* __restrict__ rp,
    const int* __restrict__ col, const float* __restrict__ bias,
    float* __restrict__ out, int n_nodes)
{
    __shared__ float exl[4][AGG_CAP][4];
    const int widx = threadIdx.x >> 6;
    const int lane = threadIdx.x & 63;
    const int n = blockIdx.x * 4 + widx;
    if (n >= n_nodes) return;

    const int e0 = rp[n], e1 = rp[n + 1];
    float4 adv = *(const float4*)&ad_[n * 4];
    float4 asn = *(const float4*)&as_[n * 4];
    float es0 = lrelu02(asn.x + adv.x), es1 = lrelu02(asn.y + adv.y);
    float es2 = lrelu02(asn.z + adv.z), es3 = lrelu02(asn.w + adv.w);

    float m0 = es0, m1 = es1, m2 = es2, m3 = es3;
    for (int e = e0 + lane; e < e1; e += 64) {
        int s = col[e];
        float4 a = *(const float4*)&as_[s * 4];
        m0 = fmaxf(m0, lrelu02(a.x + adv.x));
        m1 = fmaxf(m1, lrelu02(a.y + adv.y));
        m2 = fmaxf(m2, lrelu02(a.z + adv.z));
        m3 = fmaxf(m3, lrelu02(a.w + adv.w));
    }
#pragma unroll
    for (int off = 32; off >= 1; off >>= 1) {
        m0 = fmaxf(m0, __shfl_xor(m0, off, 64));
        m1 = fmaxf(m1, __shfl_xor(m1, off, 64));
        m2 = fmaxf(m2, __shfl_xor(m2, off, 64));
        m3 = fmaxf(m3, __shfl_xor(m3, off, 64));
    }

    float d0 = 0.f, d1 = 0.f, d2 = 0.f, d3 = 0.f;
    for (int e = e0 + lane; e < e1; e += 64) {
        int s = col[e];
        float4 a = *(const float4*)&as_[s * 4];
        float x0 = __expf(lrelu02(a.x + adv.x) - m0);
        float x1 = __expf(lrelu02(a.y + adv.y) - m1);
        float x2 = __expf(lrelu02(a.z + adv.z) - m2);
        float x3 = __expf(lrelu02(a.w + adv.w) - m3);
        int idx = e - e0;
        if (idx < AGG_CAP) {
            exl[widx][idx][0] = x0; exl[widx][idx][1] = x1;
            exl[widx][idx][2] = x2; exl[widx][idx][3] = x3;
        }
        d0 += x0; d1 += x1; d2 += x2; d3 += x3;
    }
#pragma unroll
    for (int off = 32; off >= 1; off >>= 1) {
        d0 += __shfl_xor(d0, off, 64);
        d1 += __shfl_xor(d1, off, 64);
        d2 += __shfl_xor(d2, off, 64);
        d3 += __shfl_xor(d3, off, 64);
    }
    float xs0 = __expf(es0 - m0), xs1 = __expf(es1 - m1);
    float xs2 = __expf(es2 - m2), xs3 = __expf(es3 - m3);
    d0 += xs0; d1 += xs1; d2 += xs2; d3 += xs3;
    float i0 = 1.f / (d0 + 1e-16f), i1 = 1.f / (d1 + 1e-16f);
    float i2 = 1.f / (d2 + 1e-16f), i3 = 1.f / (d3 + 1e-16f);

    const bool hi = lane >= 32;
    const int c0 = lane, c1 = lane + 64;
    float inv0 = hi ? i1 : i0, inv1 = hi ? i3 : i2;
    float mm0 = hi ? m1 : m0, mm1 = hi ? m3 : m2;
    float ad0 = hi ? adv.y : adv.x, ad1 = hi ? adv.w : adv.z;
    float ex_s0 = hi ? xs1 : xs0, ex_s1 = hi ? xs3 : xs2;

    float acc0 = ex_s0 * inv0 * hp[n * HID + c0];
    float acc1 = ex_s1 * inv1 * hp[n * HID + c1];
    for (int e = e0; e < e1; e++) {
        int s = col[e];
        int idx = e - e0;
        float e_c0, e_c1;
        if (idx < AGG_CAP) {
            e_c0 = exl[widx][idx][hi ? 1 : 0];
            e_c1 = exl[widx][idx][hi ? 3 : 2];
        } else {
            float4 a = *(const float4*)&as_[s * 4];
            e_c0 = __expf(lrelu02((hi ? a.y : a.x) + ad0) - mm0);
            e_c1 = __expf(lrelu02((hi ? a.w : a.z) + ad1) - mm1);
        }
        acc0 = fmaf(e_c0 * inv0, hp[s * HID + c0], acc0);
        acc1 = fmaf(e_c1 * inv1, hp[s * HID + c1], acc1);
    }
    out[n * HID + c0] = eluf_(acc0 + bias[c0]);
    out[n * HID + c1] = eluf_(acc1 + bias[c1]);
}

// ---------------------------------------------------------------------------
// classifier
// ---------------------------------------------------------------------------
__global__ void classifier_kernel(const float* __restrict__ x, const float* __restrict__ w,
                                  const float* __restrict__ b, float* __restrict__ out, int n)
{
    int wv = (blockIdx.x * 256 + threadIdx.x) >> 6;
    int lane = threadIdx.x & 63;
    if (wv >= n) return;
    float acc = x[wv * HID + lane] * w[lane] + x[wv * HID + 64 + lane] * w[64 + lane];
#pragma unroll
    for (int off = 32; off >= 1; off >>= 1) acc += __shfl_xor(acc, off, 64);
    if (lane == 0) out[wv] = sigmoidf_(acc + b[0]);
}

// ---------------------------------------------------------------------------
extern "C" void kernel_launch(void* const* d_in, const int* in_sizes, int n_in,
                              void* d_out, int out_size, void* d_ws, size_t ws_size,
                              hipStream_t stream)
{
    const float* x     = (const float*)d_in[0];
    const int*   ei    = (const int*)d_in[1];
    const float* w_ih  = (const float*)d_in[2];
    const float* w_hh  = (const float*)d_in[3];
    const float* b_ih  = (const float*)d_in[4];
    const float* b_hh  = (const float*)d_in[5];
    const float* g1w   = (const float*)d_in[6];
    const float* g1as  = (const float*)d_in[7];
    const float* g1ad  = (const float*)d_in[8];
    const float* g1b   = (const float*)d_in[9];
    const float* g2w   = (const float*)d_in[10];
    const float* g2as  = (const float*)d_in[11];
    const float* g2ad  = (const float*)d_in[12];
    const float* g2b   = (const float*)d_in[13];
    const float* cw    = (const float*)d_in[14];
    const float* cb    = (const float*)d_in[15];
    float* out = (float*)d_out;

    char* wsb = (char*)d_ws;
    size_t off = 0;
    auto alc = [&](size_t bytes) { size_t o = off; off += (bytes + 255) & ~(size_t)255; return o; };

    float* bufA = (float*)(wsb + alc((size_t)NP * HID * 4));
    float* bufB = (float*)(wsb + alc((size_t)NP * HID * 4));
    float* bufC = (float*)(wsb + alc((size_t)NP * HID * 4));
    float* as_  = (float*)(wsb + alc((size_t)NP * 4 * 4));
    float* ad_  = (float*)(wsb + alc((size_t)NP * 4 * 4));
    float* g1T  = (float*)(wsb + alc((size_t)128 * 128 * 4));
    float* g2T  = (float*)(wsb + alc((size_t)128 * 128 * 4));
    int*   rp   = (int*)(wsb + alc((size_t)(N_NODES + 1) * 4));
    int*   deg  = (int*)(wsb + alc((size_t)N_NODES * 4));
    int*   cur  = (int*)(wsb + alc((size_t)N_NODES * 4));
    int*   col  = (int*)(wsb + alc((size_t)NEDGE * 4));
    int*   bsum = (int*)(wsb + alc((size_t)256 * 4));

    const int* src = ei;
    const int* dst = ei + NEDGE;

    hipMemsetAsync(deg, 0, (size_t)N_NODES * 4, stream);
    hipMemsetAsync(cur, 0, (size_t)N_NODES * 4, stream);

    prep_weights<<<64, 256, 0, stream>>>(g1w, g2w, g1T, g2T);

    // CSR build (reused by both GAT layers)
    count_edges<<<NEDGE / 256, 256, 0, stream>>>(dst, deg, NEDGE);
    scan_block_sums<<<NB_SCAN, 256, 0, stream>>>(deg, bsum, N_NODES);
    scan_bsum<<<1, 256, 0, stream>>>(bsum, NB_SCAN);
    scan_final<<<NB_SCAN, 256, 0, stream>>>(deg, bsum, rp, N_NODES);
    fill_edges<<<NEDGE / 256, 256, 0, stream>>>(src, dst, rp, cur, col, NEDGE);

    // fused GRU (all 16 steps), bf16 MFMA, h -> bufA
    gru_fused<<<NP / 32, 512, 0, stream>>>(x, w_ih, w_hh, b_ih, b_hh, bufA);

    // GAT layer 1: bufA -> bufB (proj) -> bufC (agg+elu)
    gemm_proj<<<NP / 32, 256, 0, stream>>>(bufA, g1T, bufB);
    attn_coef<<<(N_NODES * 4 + 255) / 256, 256, 0, stream>>>(bufB, g1as, g1ad, as_, ad_, N_NODES);
    gat_agg<<<(N_NODES + 3) / 4, 256, 0, stream>>>(bufB, as_, ad_, rp, col, g1b, bufC, N_NODES);

    // GAT layer 2: bufC -> bufB (proj) -> bufA (agg+elu)
    gemm_proj<<<NP / 32, 256, 0, stream>>>(bufC, g2T, bufB);
    attn_coef<<<(N_NODES * 4 + 255) / 256, 256, 0, stream>>>(bufB, g2as, g2ad, as_, ad_, N_NODES);
    gat_agg<<<(N_NODES + 3) / 4, 256, 0, stream>>>(bufB, as_, ad_, rp, col, g2b, bufA, N_NODES);

    // classifier
    classifier_kernel<<<(N_NODES + 3) / 4, 256, 0, stream>>>(bufA, cw, cb, out, N_NODES);
}

// Round 3
// 1074.573 us; speedup vs baseline: 4.5918x; 1.3374x over previous
//
#include <hip/hip_runtime.h>
#include <math.h>

#define N_NODES 50000
#define NP      50048          // padded node count (multiple of 64)
#define SEQ     16
#define FIN     64
#define HID     128
#define NEDGE   1600000
#define NB_SCAN 196            // ceil(50000/256)
#define AGG_CAP 96

typedef __attribute__((ext_vector_type(8))) short short8;   // 8 bf16 = 4 VGPRs
typedef __attribute__((ext_vector_type(4))) float f32x4;

__device__ __forceinline__ float lrelu02(float v) { return v > 0.f ? v : 0.2f * v; }
__device__ __forceinline__ float frcp(float v) { return __builtin_amdgcn_rcpf(v); }
__device__ __forceinline__ float sigmoidf_(float v) { return frcp(1.f + __expf(-v)); }
__device__ __forceinline__ float eluf_(float v) { return v > 0.f ? v : (__expf(v) - 1.f); }

__device__ __forceinline__ short f2bf(float f) {
    unsigned u = __builtin_bit_cast(unsigned, f);
    u = (u + 0x7FFF + ((u >> 16) & 1)) >> 16;   // RNE
    return (short)u;
}
__device__ __forceinline__ short8 pack8(float4 a, float4 b) {
    short8 r;
    r[0] = f2bf(a.x); r[1] = f2bf(a.y); r[2] = f2bf(a.z); r[3] = f2bf(a.w);
    r[4] = f2bf(b.x); r[5] = f2bf(b.y); r[6] = f2bf(b.z); r[7] = f2bf(b.w);
    return r;
}

// ---------------------------------------------------------------------------
// Fused GRU: one block = 32 nodes, all 16 timesteps. 512 threads = 8 waves.
// Wave w owns ch slice [16w,16w+16) of ALL THREE gates (cols 16w / 128+16w /
// 256+16w). MFMA C-layout (col=lane&15, row=quad*4+reg) then keeps r,z,i_n,h_n
// for a (node,ch) pair in one lane -> gate math is register-only.
// Only h crosses node<->ch: bf16 double-buffered hA in LDS, 1 barrier/step.
// x for step t+1 is prefetched from global before step t's MFMAs.
// ---------------------------------------------------------------------------
__global__ __launch_bounds__(512, 2) void gru_fused(
    const float* __restrict__ x,     // [N][16][64]
    const float* __restrict__ w_ih,  // [384][64]
    const float* __restrict__ w_hh,  // [384][128]
    const float* __restrict__ b_ih,  // [384]
    const float* __restrict__ b_hh,  // [384]
    float* __restrict__ hout)        // [NP][128]
{
    __shared__ __align__(16) short hA[2][32][136];  // h bf16, A-frag layout

    const int tid  = threadIdx.x;
    const int wave = tid >> 6;
    const int lane = tid & 63;
    const int q    = lane >> 4;      // quad 0..3
    const int rl   = lane & 15;
    const int n0   = blockIdx.x * 32;
    const int ch   = wave * 16 + rl; // this lane's channel (output col within gate)

    // ---- resident weight B-fragments (bf16): 3 gates x this ch-slice ----
    // gate g row base: g*128 + ch ; B[n=rl][k=q*8+j], kc chunks of 32
    short8 whhf[3][4];   // [gate][kc] K=128
    short8 wihf[3][2];   // [gate][kc] K=64
#pragma unroll
    for (int g = 0; g < 3; g++) {
        int row = g * 128 + ch;
#pragma unroll
        for (int kc = 0; kc < 4; kc++) {
            const float* p = w_hh + row * HID + kc * 32 + q * 8;
            whhf[g][kc] = pack8(*(const float4*)p, *(const float4*)(p + 4));
        }
#pragma unroll
        for (int kc = 0; kc < 2; kc++) {
            const float* p = w_ih + row * FIN + kc * 32 + q * 8;
            wihf[g][kc] = pack8(*(const float4*)p, *(const float4*)(p + 4));
        }
    }

    // per-lane biases
    const float br  = b_ih[ch] + b_hh[ch];
    const float bz  = b_ih[128 + ch] + b_hh[128 + ch];
    const float bin = b_ih[256 + ch];
    const float bhn = b_hh[256 + ch];

    // node ids this lane loads x for (A-frag row = rl)
    int gn[2];
#pragma unroll
    for (int mt = 0; mt < 2; mt++) {
        int g = n0 + mt * 16 + rl;
        gn[mt] = (g > N_NODES - 1) ? N_NODES - 1 : g;
    }

    // h state: lane holds (node = mt*16 + q*4 + reg, this ch)
    float hreg[2][4];
#pragma unroll
    for (int mt = 0; mt < 2; mt++)
#pragma unroll
        for (int r = 0; r < 4; r++) hreg[mt][r] = 0.f;

    // prefetch x for t=0
    float4 xr[2][2][2];
    auto load_x = [&](int t) {
#pragma unroll
        for (int mt = 0; mt < 2; mt++) {
            const float* xp = x + ((size_t)gn[mt] * SEQ + t) * FIN + q * 8;
#pragma unroll
            for (int kc = 0; kc < 2; kc++) {
                xr[mt][kc][0] = *(const float4*)(xp + kc * 32);
                xr[mt][kc][1] = *(const float4*)(xp + kc * 32 + 4);
            }
        }
    };
    load_x(0);
    short8 xf[2][2];
#pragma unroll
    for (int mt = 0; mt < 2; mt++)
#pragma unroll
        for (int kc = 0; kc < 2; kc++)
            xf[mt][kc] = pack8(xr[mt][kc][0], xr[mt][kc][1]);

    for (int t = 0; t < SEQ; t++) {
        // A-frags for H (prev step) from LDS
        short8 hf[2][4];
        if (t > 0) {
            const int b = (t - 1) & 1;
#pragma unroll
            for (int mt = 0; mt < 2; mt++)
#pragma unroll
                for (int kc = 0; kc < 4; kc++)
                    hf[mt][kc] = *(const short8*)&hA[b][mt * 16 + rl][kc * 32 + q * 8];
        }

        // prefetch x for next step (independent of MFMAs below)
        if (t + 1 < SEQ) load_x(t + 1);

        // MFMAs: accr/accz get x(K64)+h(K128); accin x only; acchn h only
        f32x4 accr[2], accz[2], accin[2], acchn[2];
#pragma unroll
        for (int mt = 0; mt < 2; mt++) {
            accr[mt] = (f32x4)0.f; accz[mt] = (f32x4)0.f;
            accin[mt] = (f32x4)0.f; acchn[mt] = (f32x4)0.f;
#pragma unroll
            for (int kc = 0; kc < 2; kc++) {
                accr[mt]  = __builtin_amdgcn_mfma_f32_16x16x32_bf16(xf[mt][kc], wihf[0][kc], accr[mt], 0, 0, 0);
                accz[mt]  = __builtin_amdgcn_mfma_f32_16x16x32_bf16(xf[mt][kc], wihf[1][kc], accz[mt], 0, 0, 0);
                accin[mt] = __builtin_amdgcn_mfma_f32_16x16x32_bf16(xf[mt][kc], wihf[2][kc], accin[mt], 0, 0, 0);
            }
            if (t > 0) {
#pragma unroll
                for (int kc = 0; kc < 4; kc++) {
                    accr[mt]  = __builtin_amdgcn_mfma_f32_16x16x32_bf16(hf[mt][kc], whhf[0][kc], accr[mt], 0, 0, 0);
                    accz[mt]  = __builtin_amdgcn_mfma_f32_16x16x32_bf16(hf[mt][kc], whhf[1][kc], accz[mt], 0, 0, 0);
                    acchn[mt] = __builtin_amdgcn_mfma_f32_16x16x32_bf16(hf[mt][kc], whhf[2][kc], acchn[mt], 0, 0, 0);
                }
            }
        }

        // pack next-step x (loads have landed by now)
        if (t + 1 < SEQ) {
#pragma unroll
            for (int mt = 0; mt < 2; mt++)
#pragma unroll
                for (int kc = 0; kc < 2; kc++)
                    xf[mt][kc] = pack8(xr[mt][kc][0], xr[mt][kc][1]);
        }

        // gate math — all in registers; write new h (bf16) to hA[t&1]
        const int b = t & 1;
#pragma unroll
        for (int mt = 0; mt < 2; mt++)
#pragma unroll
            for (int r = 0; r < 4; r++) {
                float rg = sigmoidf_(accr[mt][r] + br);
                float zg = sigmoidf_(accz[mt][r] + bz);
                float a  = accin[mt][r] + bin + rg * (acchn[mt][r] + bhn);
                float e  = __expf(2.f * a);
                float nn = 1.f - 2.f * frcp(e + 1.f);
                float h  = (1.f - zg) * nn + zg * hreg[mt][r];
                hreg[mt][r] = h;
                hA[b][mt * 16 + q * 4 + r][ch] = f2bf(h);
            }
        __syncthreads();
    }

    // final h to global (fp32)
#pragma unroll
    for (int mt = 0; mt < 2; mt++)
#pragma unroll
        for (int r = 0; r < 4; r++)
            hout[(size_t)(n0 + mt * 16 + q * 4 + r) * HID + ch] = hreg[mt][r];
}

// ---------------------------------------------------------------------------
// weight prep for GAT projections: w[g][k] -> [k][g]
// ---------------------------------------------------------------------------
__global__ void prep_weights(const float* __restrict__ g1w, const float* __restrict__ g2w,
                             float* __restrict__ g1T, float* __restrict__ g2T)
{
    int i = blockIdx.x * 256 + threadIdx.x;
    if (i < 128 * 128) {
        int k = i >> 7, g = i & 127;
        g1T[i] = g1w[g * 128 + k];
        g2T[i] = g2w[g * 128 + k];
    }
}

// ---------------------------------------------------------------------------
// CSR build
// ---------------------------------------------------------------------------
__global__ void count_edges(const int* __restrict__ dst, int* __restrict__ deg, int e)
{
    int i = blockIdx.x * 256 + threadIdx.x;
    if (i < e) atomicAdd(&deg[dst[i]], 1);
}

__device__ __forceinline__ int block_scan_inc(int v)
{
    int tid = threadIdx.x, lane = tid & 63, w = tid >> 6;
#pragma unroll
    for (int off = 1; off < 64; off <<= 1) {
        int tmp = __shfl_up(v, off, 64);
        if (lane >= off) v += tmp;
    }
    __shared__ int wsum[4];
    if (lane == 63) wsum[w] = v;
    __syncthreads();
    int add = 0;
    for (int i = 0; i < w; i++) add += wsum[i];
    return v + add;
}

__global__ void scan_block_sums(const int* __restrict__ deg, int* __restrict__ bsum, int n)
{
    int i = blockIdx.x * 256 + threadIdx.x;
    int v = (i < n) ? deg[i] : 0;
#pragma unroll
    for (int off = 32; off >= 1; off >>= 1) v += __shfl_xor(v, off, 64);
    __shared__ int ws[4];
    if ((threadIdx.x & 63) == 0) ws[threadIdx.x >> 6] = v;
    __syncthreads();
    if (threadIdx.x == 0) bsum[blockIdx.x] = ws[0] + ws[1] + ws[2] + ws[3];
}

__global__ void scan_bsum(int* __restrict__ bsum, int nb)
{
    int tid = threadIdx.x;
    int v = (tid < nb) ? bsum[tid] : 0;
    v = block_scan_inc(v);
    if (tid < nb) bsum[tid] = v;
}

__global__ void scan_final(const int* __restrict__ deg, const int* __restrict__ bsum,
                           int* __restrict__ rp, int n)
{
    int i = blockIdx.x * 256 + threadIdx.x;
    int v = (i < n) ? deg[i] : 0;
    int s = block_scan_inc(v);
    int add = (blockIdx.x > 0) ? bsum[blockIdx.x - 1] : 0;
    if (i < n) rp[i + 1] = s + add;
    if (i == 0) rp[0] = 0;
}

__global__ void fill_edges(const int* __restrict__ src, const int* __restrict__ dst,
                           const int* __restrict__ rp, int* __restrict__ cur,
                           int* __restrict__ col, int e)
{
    int i = blockIdx.x * 256 + threadIdx.x;
    if (i < e) {
        int d = dst[i];
        int pos = atomicAdd(&cur[d], 1);
        col[rp[d] + pos] = src[i];
    }
}

// ---------------------------------------------------------------------------
// GAT projection: hp = x @ wT  (128x128), 32 nodes/block  (fp32 for accuracy)
// ---------------------------------------------------------------------------
__global__ __launch_bounds__(256) void gemm_proj(
    const float* __restrict__ x, const float* __restrict__ wT, float* __restrict__ hp)
{
    __shared__ float xt[32][129];
    __shared__ float wt[32][128];
    const int tid = threadIdx.x;
    const int tx = tid & 7;       // 8 node groups of 4
    const int ty = tid >> 3;      // 32 out groups of 4
    const int n0 = blockIdx.x * 32;
    float acc[4][4];
#pragma unroll
    for (int i = 0; i < 4; i++)
#pragma unroll
        for (int j = 0; j < 4; j++) acc[i][j] = 0.f;

    for (int k0 = 0; k0 < 128; k0 += 32) {
        __syncthreads();
#pragma unroll
        for (int i = 0; i < 4; i++) {
            int flat = tid + i * 256;
            int n = flat >> 5, k = flat & 31;
            xt[n][k] = x[(n0 + n) * HID + k0 + k];
        }
#pragma unroll
        for (int i = 0; i < 16; i++) {
            int flat = tid + i * 256;
            int kk = flat >> 7, g = flat & 127;
            wt[kk][g] = wT[(k0 + kk) * HID + g];
        }
        __syncthreads();
#pragma unroll 8
        for (int kk = 0; kk < 32; kk++) {
            float xv[4];
#pragma unroll
            for (int i = 0; i < 4; i++) xv[i] = xt[tx * 4 + i][kk];
            float4 wv = *(const float4*)&wt[kk][ty * 4];
#pragma unroll
            for (int i = 0; i < 4; i++) {
                acc[i][0] = fmaf(xv[i], wv.x, acc[i][0]);
                acc[i][1] = fmaf(xv[i], wv.y, acc[i][1]);
                acc[i][2] = fmaf(xv[i], wv.z, acc[i][2]);
                acc[i][3] = fmaf(xv[i], wv.w, acc[i][3]);
            }
        }
    }
#pragma unroll
    for (int i = 0; i < 4; i++)
        *(float4*)&hp[(n0 + tx * 4 + i) * HID + ty * 4] =
            make_float4(acc[i][0], acc[i][1], acc[i][2], acc[i][3]);
}

// ---------------------------------------------------------------------------
// attention coefficients
// ---------------------------------------------------------------------------
__global__ void attn_coef(const float* __restrict__ hp, const float* __restrict__ a_src,
                          const float* __restrict__ a_dst,
                          float* __restrict__ as_, float* __restrict__ ad_, int n)
{
    int idx = blockIdx.x * 256 + threadIdx.x;
    if (idx >= n * 4) return;
    int node = idx >> 2, hh = idx & 3;
    const float* hr = hp + node * HID + hh * 32;
    const float* ar = a_src + hh * 32;
    const float* br = a_dst + hh * 32;
    float s = 0.f, d = 0.f;
#pragma unroll
    for (int j = 0; j < 32; j += 4) {
        float4 hv = *(const float4*)&hr[j];
        float4 av = *(const float4*)&ar[j];
        float4 bv = *(const float4*)&br[j];
        s += hv.x * av.x + hv.y * av.y + hv.z * av.z + hv.w * av.w;
        d += hv.x * bv.x + hv.y * bv.y + hv.z * bv.z + hv.w * bv.w;
    }
    as_[idx] = s;
    ad_[idx] = d;
}

// ---------------------------------------------------------------------------
// GAT aggregation: one wave per dst node, CSR + implicit self-loop.
// No max-pass (softmax shift is a mathematical no-op; logits are O(5), fp32
// exp is safe). denom folded out of the inner loop. If CLF: fuse classifier
// (layer-2 features never hit HBM).
// ---------------------------------------------------------------------------
template <bool CLF>
__global__ __launch_bounds__(256) void gat_agg(
    const float* __restrict__ hp, const float* __restrict__ as_,
    const float* __restrict__ ad_, const int* __restrict__ rp,
    const int* __restrict__ col, const float* __restrict__ bias,
    float* __restrict__ out, const float* __restrict__ cw,
    const float* __restrict__ cb, int n_nodes)
{
    __shared__ float exl[4][AGG_CAP][4];
    const int widx = threadIdx.x >> 6;
    const int lane = threadIdx.x & 63;
    const int n = blockIdx.x * 4 + widx;
    if (n >= n_nodes) return;

    const int e0 = rp[n], e1 = rp[n + 1];
    const int deg = e1 - e0;
    float4 adv = *(const float4*)&ad_[n * 4];
    float4 asn = *(const float4*)&as_[n * 4];
    // self-loop exp
    float xs0 = __expf(lrelu02(asn.x + adv.x)), xs1 = __expf(lrelu02(asn.y + adv.y));
    float xs2 = __expf(lrelu02(asn.z + adv.z)), xs3 = __expf(lrelu02(asn.w + adv.w));

    // phase A: exp per edge (lane-strided), cache in LDS, accumulate denoms
    float d0 = 0.f, d1 = 0.f, d2 = 0.f, d3 = 0.f;
    for (int e = e0 + lane; e < e1; e += 64) {
        int s = col[e];
        float4 a = *(const float4*)&as_[s * 4];
        float x0 = __expf(lrelu02(a.x + adv.x));
        float x1 = __expf(lrelu02(a.y + adv.y));
        float x2 = __expf(lrelu02(a.z + adv.z));
        float x3 = __expf(lrelu02(a.w + adv.w));
        int idx = e - e0;
        if (idx < AGG_CAP) {
            exl[widx][idx][0] = x0; exl[widx][idx][1] = x1;
            exl[widx][idx][2] = x2; exl[widx][idx][3] = x3;
        }
        d0 += x0; d1 += x1; d2 += x2; d3 += x3;
    }
#pragma unroll
    for (int off = 32; off >= 1; off >>= 1) {
        d0 += __shfl_xor(d0, off, 64);
        d1 += __shfl_xor(d1, off, 64);
        d2 += __shfl_xor(d2, off, 64);
        d3 += __shfl_xor(d3, off, 64);
    }
    d0 += xs0; d1 += xs1; d2 += xs2; d3 += xs3;
    float i0 = frcp(d0 + 1e-16f), i1 = frcp(d1 + 1e-16f);
    float i2 = frcp(d2 + 1e-16f), i3 = frcp(d3 + 1e-16f);

    // phase B: weighted sum; lane owns channels c0 = lane, c1 = lane + 64
    const bool hi = lane >= 32;
    const int c0 = lane, c1 = lane + 64;
    const int s0sel = hi ? 1 : 0, s1sel = hi ? 3 : 2;
    float inv0 = hi ? i1 : i0, inv1 = hi ? i3 : i2;
    float ad0 = hi ? adv.y : adv.x, ad1 = hi ? adv.w : adv.z;
    float ex_s0 = hi ? xs1 : xs0, ex_s1 = hi ? xs3 : xs2;

    float acc0 = ex_s0 * hp[n * HID + c0];
    float acc1 = ex_s1 * hp[n * HID + c1];

    if (deg <= AGG_CAP) {
        int e = e0;
        for (; e + 4 <= e1; e += 4) {
            int s_[4]; float w0_[4], w1_[4], h0_[4], h1_[4];
#pragma unroll
            for (int u = 0; u < 4; u++) {
                s_[u] = col[e + u];
                int idx = e + u - e0;
                w0_[u] = exl[widx][idx][s0sel];
                w1_[u] = exl[widx][idx][s1sel];
            }
#pragma unroll
            for (int u = 0; u < 4; u++) {
                h0_[u] = hp[s_[u] * HID + c0];
                h1_[u] = hp[s_[u] * HID + c1];
            }
#pragma unroll
            for (int u = 0; u < 4; u++) {
                acc0 = fmaf(w0_[u], h0_[u], acc0);
                acc1 = fmaf(w1_[u], h1_[u], acc1);
            }
        }
        for (; e < e1; e++) {
            int s = col[e];
            int idx = e - e0;
            acc0 = fmaf(exl[widx][idx][s0sel], hp[s * HID + c0], acc0);
            acc1 = fmaf(exl[widx][idx][s1sel], hp[s * HID + c1], acc1);
        }
    } else {
        for (int e = e0; e < e1; e++) {
            int s = col[e];
            int idx = e - e0;
            float e_c0, e_c1;
            if (idx < AGG_CAP) {
                e_c0 = exl[widx][idx][s0sel];
                e_c1 = exl[widx][idx][s1sel];
            } else {
                float4 a = *(const float4*)&as_[s * 4];
                e_c0 = __expf(lrelu02((hi ? a.y : a.x) + ad0));
                e_c1 = __expf(lrelu02((hi ? a.w : a.z) + ad1));
            }
            acc0 = fmaf(e_c0, hp[s * HID + c0], acc0);
            acc1 = fmaf(e_c1, hp[s * HID + c1], acc1);
        }
    }

    float o0 = eluf_(acc0 * inv0 + bias[c0]);
    float o1 = eluf_(acc1 * inv1 + bias[c1]);
    if (CLF) {
        float v = o0 * cw[c0] + o1 * cw[c1];
#pragma unroll
        for (int off = 32; off >= 1; off >>= 1) v += __shfl_xor(v, off, 64);
        if (lane == 0) out[n] = sigmoidf_(v + cb[0]);
    } else {
        out[n * HID + c0] = o0;
        out[n * HID + c1] = o1;
    }
}

// ---------------------------------------------------------------------------
extern "C" void kernel_launch(void* const* d_in, const int* in_sizes, int n_in,
                              void* d_out, int out_size, void* d_ws, size_t ws_size,
                              hipStream_t stream)
{
    const float* x     = (const float*)d_in[0];
    const int*   ei    = (const int*)d_in[1];
    const float* w_ih  = (const float*)d_in[2];
    const float* w_hh  = (const float*)d_in[3];
    const float* b_ih  = (const float*)d_in[4];
    const float* b_hh  = (const float*)d_in[5];
    const float* g1w   = (const float*)d_in[6];
    const float* g1as  = (const float*)d_in[7];
    const float* g1ad  = (const float*)d_in[8];
    const float* g1b   = (const float*)d_in[9];
    const float* g2w   = (const float*)d_in[10];
    const float* g2as  = (const float*)d_in[11];
    const float* g2ad  = (const float*)d_in[12];
    const float* g2b   = (const float*)d_in[13];
    const float* cw    = (const float*)d_in[14];
    const float* cb    = (const float*)d_in[15];
    float* out = (float*)d_out;

    char* wsb = (char*)d_ws;
    size_t off = 0;
    auto alc = [&](size_t bytes) { size_t o = off; off += (bytes + 255) & ~(size_t)255; return o; };

    float* bufA = (float*)(wsb + alc((size_t)NP * HID * 4));
    float* bufB = (float*)(wsb + alc((size_t)NP * HID * 4));
    float* bufC = (float*)(wsb + alc((size_t)NP * HID * 4));
    float* as_  = (float*)(wsb + alc((size_t)NP * 4 * 4));
    float* ad_  = (float*)(wsb + alc((size_t)NP * 4 * 4));
    float* g1T  = (float*)(wsb + alc((size_t)128 * 128 * 4));
    float* g2T  = (float*)(wsb + alc((size_t)128 * 128 * 4));
    int*   rp   = (int*)(wsb + alc((size_t)(N_NODES + 1) * 4));
    int*   deg  = (int*)(wsb + alc((size_t)N_NODES * 4));
    int*   cur  = (int*)(wsb + alc((size_t)N_NODES * 4));
    int*   col  = (int*)(wsb + alc((size_t)NEDGE * 4));
    int*   bsum = (int*)(wsb + alc((size_t)256 * 4));

    const int* src = ei;
    const int* dst = ei + NEDGE;

    hipMemsetAsync(deg, 0, (size_t)N_NODES * 4, stream);
    hipMemsetAsync(cur, 0, (size_t)N_NODES * 4, stream);

    prep_weights<<<64, 256, 0, stream>>>(g1w, g2w, g1T, g2T);

    // CSR build (reused by both GAT layers)
    count_edges<<<NEDGE / 256, 256, 0, stream>>>(dst, deg, NEDGE);
    scan_block_sums<<<NB_SCAN, 256, 0, stream>>>(deg, bsum, N_NODES);
    scan_bsum<<<1, 256, 0, stream>>>(bsum, NB_SCAN);
    scan_final<<<NB_SCAN, 256, 0, stream>>>(deg, bsum, rp, N_NODES);
    fill_edges<<<NEDGE / 256, 256, 0, stream>>>(src, dst, rp, cur, col, NEDGE);

    // fused GRU (all 16 steps), bf16 MFMA, h -> bufA
    gru_fused<<<NP / 32, 512, 0, stream>>>(x, w_ih, w_hh, b_ih, b_hh, bufA);

    // GAT layer 1: bufA -> bufB (proj) -> bufC (agg+elu)
    gemm_proj<<<NP / 32, 256, 0, stream>>>(bufA, g1T, bufB);
    attn_coef<<<(N_NODES * 4 + 255) / 256, 256, 0, stream>>>(bufB, g1as, g1ad, as_, ad_, N_NODES);
    gat_agg<false><<<(N_NODES + 3) / 4, 256, 0, stream>>>(bufB, as_, ad_, rp, col, g1b, bufC,
                                                          nullptr, nullptr, N_NODES);

    // GAT layer 2: bufC -> bufB (proj); agg fused with classifier -> out
    gemm_proj<<<NP / 32, 256, 0, stream>>>(bufC, g2T, bufB);
    attn_coef<<<(N_NODES * 4 + 255) / 256, 256, 0, stream>>>(bufB, g2as, g2ad, as_, ad_, N_NODES);
    gat_agg<true><<<(N_NODES + 3) / 4, 256, 0, stream>>>(bufB, as_, ad_, rp, col, g2b, out,
                                                         cw, cb, N_NODES);
}

// Round 4
// 872.592 us; speedup vs baseline: 5.6546x; 1.2315x over previous
//
#include <hip/hip_runtime.h>
#include <hip/hip_bf16.h>
#include <hip/hip_fp16.h>
#include <math.h>

#define N_NODES 50000
#define NP      50048          // padded node count (multiple of 64)
#define SEQ     16
#define FIN     64
#define HID     128
#define NEDGE   1600000
#define NB_SCAN 196            // ceil(50000/256)
#define AGG_CAP 96

typedef __attribute__((ext_vector_type(8))) short short8;   // 8 bf16 = 4 VGPRs
typedef __attribute__((ext_vector_type(4))) float f32x4;

__device__ __forceinline__ float lrelu02(float v) { return v > 0.f ? v : 0.2f * v; }
__device__ __forceinline__ float frcp(float v) { return __builtin_amdgcn_rcpf(v); }
__device__ __forceinline__ float sigmoidf_(float v) { return frcp(1.f + __expf(-v)); }
__device__ __forceinline__ float eluf_(float v) { return v > 0.f ? v : (__expf(v) - 1.f); }

// packed fp32x2 -> bf16x2 (v_cvt_pk_bf16_f32 on gfx950), RNE
__device__ __forceinline__ unsigned bfpk(float lo, float hi) {
    union { __hip_bfloat162 h; unsigned u; } c;
    c.h = __float22bfloat162_rn(make_float2(lo, hi));
    return c.u;
}
// packed fp32x2 -> fp16x2
__device__ __forceinline__ unsigned hfpk(float lo, float hi) {
    union { __half2 h; unsigned u; } c;
    c.h = __float22half2_rn(make_float2(lo, hi));
    return c.u;
}
__device__ __forceinline__ float2 h2f2(unsigned u) {
    union { unsigned u; __half2 h; } c;
    c.u = u;
    return __half22float2(c.h);
}
__device__ __forceinline__ short8 pack8(float4 a, float4 b) {
    union { short8 s; unsigned u[4]; } r;
    r.u[0] = bfpk(a.x, a.y); r.u[1] = bfpk(a.z, a.w);
    r.u[2] = bfpk(b.x, b.y); r.u[3] = bfpk(b.z, b.w);
    return r.s;
}

// ---------------------------------------------------------------------------
// Fused GRU: one block = 32 nodes, all 16 timesteps. 512 threads = 8 waves.
// Wave w owns ch slice [16w,16w+16) of ALL THREE gates. MFMA C-layout keeps
// r,z,i_n,h_n for a (node,ch) pair in one lane -> gate math register-only.
// x tile staged to LDS as bf16 ONCE per block per step (each thread: one
// float4 + 2 packed cvt + 1 ds_write_b64), A-frags via ds_read_b128.
// h crosses node<->ch through double-buffered bf16 hA. 1 barrier/step.
// ---------------------------------------------------------------------------
__global__ __launch_bounds__(512, 2) void gru_fused(
    const float* __restrict__ x,     // [N][16][64]
    const float* __restrict__ w_ih,  // [384][64]
    const float* __restrict__ w_hh,  // [384][128]
    const float* __restrict__ b_ih,  // [384]
    const float* __restrict__ b_hh,  // [384]
    float* __restrict__ hout)        // [NP][128]
{
    // row stride 72 shorts = 144 B (16-aligned for ds_read_b128, stride-4 banks)
    __shared__ __align__(16) short hA[2][32][72];
    __shared__ __align__(16) short xB[2][32][72];

    const int tid  = threadIdx.x;
    const int wave = tid >> 6;
    const int lane = tid & 63;
    const int q    = lane >> 4;      // quad 0..3
    const int rl   = lane & 15;
    const int n0   = blockIdx.x * 32;
    const int ch   = wave * 16 + rl; // channel within gate

    // ---- resident weight B-fragments (bf16): 3 gates x this ch-slice ----
    short8 whhf[3][4];   // [gate][kc] K=128
    short8 wihf[3][2];   // [gate][kc] K=64
#pragma unroll
    for (int g = 0; g < 3; g++) {
        int row = g * 128 + ch;
#pragma unroll
        for (int kc = 0; kc < 4; kc++) {
            const float* p = w_hh + row * HID + kc * 32 + q * 8;
            whhf[g][kc] = pack8(*(const float4*)p, *(const float4*)(p + 4));
        }
#pragma unroll
        for (int kc = 0; kc < 2; kc++) {
            const float* p = w_ih + row * FIN + kc * 32 + q * 8;
            wihf[g][kc] = pack8(*(const float4*)p, *(const float4*)(p + 4));
        }
    }

    // per-lane biases
    const float br  = b_ih[ch] + b_hh[ch];
    const float bz  = b_ih[128 + ch] + b_hh[128 + ch];
    const float bin = b_ih[256 + ch];
    const float bhn = b_hh[256 + ch];

    // staging assignment: thread owns 4 consecutive floats of the 32x64 tile
    const int sn = tid >> 4;          // node 0..31
    const int sk = (tid & 15) * 4;    // k 0..60
    int sgn = n0 + sn; if (sgn > N_NODES - 1) sgn = N_NODES - 1;
    const float* xsp = x + (size_t)sgn * SEQ * FIN + sk;

    // h state: lane holds (node = mt*16 + q*4 + r, this ch)
    float hreg[2][4];
#pragma unroll
    for (int mt = 0; mt < 2; mt++)
#pragma unroll
        for (int r = 0; r < 4; r++) hreg[mt][r] = 0.f;

    // stage x(t=0)
    {
        float4 v = *(const float4*)(xsp);
        int2 pv;
        pv.x = (int)bfpk(v.x, v.y);
        pv.y = (int)bfpk(v.z, v.w);
        *(int2*)&xB[0][sn][sk] = pv;
    }
    __syncthreads();

    for (int t = 0; t < SEQ; t++) {
        const int xb = t & 1;
        // A-frags from LDS
        short8 xf[2][2], hf[2][4];
#pragma unroll
        for (int mt = 0; mt < 2; mt++)
#pragma unroll
            for (int kc = 0; kc < 2; kc++)
                xf[mt][kc] = *(const short8*)&xB[xb][mt * 16 + rl][kc * 32 + q * 8];
        if (t > 0) {
            const int hb = (t - 1) & 1;
#pragma unroll
            for (int mt = 0; mt < 2; mt++)
#pragma unroll
                for (int kc = 0; kc < 4; kc++)
                    hf[mt][kc] = *(const short8*)&hA[hb][mt * 16 + rl][kc * 32 + q * 8];
        }

        // issue next-step x load early (latency hidden by MFMAs)
        float4 xs;
        if (t + 1 < SEQ) xs = *(const float4*)(xsp + (t + 1) * FIN);

        // MFMAs
        f32x4 accr[2], accz[2], accin[2], acchn[2];
#pragma unroll
        for (int mt = 0; mt < 2; mt++) {
            accr[mt] = (f32x4)0.f; accz[mt] = (f32x4)0.f;
            accin[mt] = (f32x4)0.f; acchn[mt] = (f32x4)0.f;
#pragma unroll
            for (int kc = 0; kc < 2; kc++) {
                accr[mt]  = __builtin_amdgcn_mfma_f32_16x16x32_bf16(xf[mt][kc], wihf[0][kc], accr[mt], 0, 0, 0);
                accz[mt]  = __builtin_amdgcn_mfma_f32_16x16x32_bf16(xf[mt][kc], wihf[1][kc], accz[mt], 0, 0, 0);
                accin[mt] = __builtin_amdgcn_mfma_f32_16x16x32_bf16(xf[mt][kc], wihf[2][kc], accin[mt], 0, 0, 0);
            }
            if (t > 0) {
#pragma unroll
                for (int kc = 0; kc < 4; kc++) {
                    accr[mt]  = __builtin_amdgcn_mfma_f32_16x16x32_bf16(hf[mt][kc], whhf[0][kc], accr[mt], 0, 0, 0);
                    accz[mt]  = __builtin_amdgcn_mfma_f32_16x16x32_bf16(hf[mt][kc], whhf[1][kc], accz[mt], 0, 0, 0);
                    acchn[mt] = __builtin_amdgcn_mfma_f32_16x16x32_bf16(hf[mt][kc], whhf[2][kc], acchn[mt], 0, 0, 0);
                }
            }
        }

        // stage x(t+1) into the other buffer (read next step, after barrier)
        if (t + 1 < SEQ) {
            int2 pv;
            pv.x = (int)bfpk(xs.x, xs.y);
            pv.y = (int)bfpk(xs.z, xs.w);
            *(int2*)&xB[(t + 1) & 1][sn][sk] = pv;
        }

        // gate math in registers; write new h (bf16, pair-packed) to hA[t&1]
        const int b = t & 1;
#pragma unroll
        for (int mt = 0; mt < 2; mt++) {
            float hv[4];
#pragma unroll
            for (int r = 0; r < 4; r++) {
                float rg = sigmoidf_(accr[mt][r] + br);
                float zg = sigmoidf_(accz[mt][r] + bz);
                float a  = accin[mt][r] + bin + rg * (acchn[mt][r] + bhn);
                float e  = __expf(2.f * a);
                float nn = 1.f - 2.f * frcp(e + 1.f);
                float h  = zg * (hreg[mt][r] - nn) + nn;
                hreg[mt][r] = h;
                hv[r] = h;
            }
            unsigned u01 = bfpk(hv[0], hv[1]);
            unsigned u23 = bfpk(hv[2], hv[3]);
            const int nb = mt * 16 + q * 4;
            hA[b][nb + 0][ch] = (short)(u01 & 0xFFFF);
            hA[b][nb + 1][ch] = (short)(u01 >> 16);
            hA[b][nb + 2][ch] = (short)(u23 & 0xFFFF);
            hA[b][nb + 3][ch] = (short)(u23 >> 16);
        }
        __syncthreads();
    }

    // final h to global (fp32)
#pragma unroll
    for (int mt = 0; mt < 2; mt++)
#pragma unroll
        for (int r = 0; r < 4; r++)
            hout[(size_t)(n0 + mt * 16 + q * 4 + r) * HID + ch] = hreg[mt][r];
}

// ---------------------------------------------------------------------------
// weight prep for GAT projections: w[g][k] -> [k][g]
// ---------------------------------------------------------------------------
__global__ void prep_weights(const float* __restrict__ g1w, const float* __restrict__ g2w,
                             float* __restrict__ g1T, float* __restrict__ g2T)
{
    int i = blockIdx.x * 256 + threadIdx.x;
    if (i < 128 * 128) {
        int k = i >> 7, g = i & 127;
        g1T[i] = g1w[g * 128 + k];
        g2T[i] = g2w[g * 128 + k];
    }
}

// ---------------------------------------------------------------------------
// CSR build
// ---------------------------------------------------------------------------
__global__ void count_edges(const int* __restrict__ dst, int* __restrict__ deg, int e)
{
    int i = blockIdx.x * 256 + threadIdx.x;
    if (i < e) atomicAdd(&deg[dst[i]], 1);
}

__device__ __forceinline__ int block_scan_inc(int v)
{
    int tid = threadIdx.x, lane = tid & 63, w = tid >> 6;
#pragma unroll
    for (int off = 1; off < 64; off <<= 1) {
        int tmp = __shfl_up(v, off, 64);
        if (lane >= off) v += tmp;
    }
    __shared__ int wsum[4];
    if (lane == 63) wsum[w] = v;
    __syncthreads();
    int add = 0;
    for (int i = 0; i < w; i++) add += wsum[i];
    return v + add;
}

__global__ void scan_block_sums(const int* __restrict__ deg, int* __restrict__ bsum, int n)
{
    int i = blockIdx.x * 256 + threadIdx.x;
    int v = (i < n) ? deg[i] : 0;
#pragma unroll
    for (int off = 32; off >= 1; off >>= 1) v += __shfl_xor(v, off, 64);
    __shared__ int ws[4];
    if ((threadIdx.x & 63) == 0) ws[threadIdx.x >> 6] = v;
    __syncthreads();
    if (threadIdx.x == 0) bsum[blockIdx.x] = ws[0] + ws[1] + ws[2] + ws[3];
}

__global__ void scan_bsum(int* __restrict__ bsum, int nb)
{
    int tid = threadIdx.x;
    int v = (tid < nb) ? bsum[tid] : 0;
    v = block_scan_inc(v);
    if (tid < nb) bsum[tid] = v;
}

__global__ void scan_final(const int* __restrict__ deg, const int* __restrict__ bsum,
                           int* __restrict__ rp, int n)
{
    int i = blockIdx.x * 256 + threadIdx.x;
    int v = (i < n) ? deg[i] : 0;
    int s = block_scan_inc(v);
    int add = (blockIdx.x > 0) ? bsum[blockIdx.x - 1] : 0;
    if (i < n) rp[i + 1] = s + add;
    if (i == 0) rp[0] = 0;
}

__global__ void fill_edges(const int* __restrict__ src, const int* __restrict__ dst,
                           const int* __restrict__ rp, int* __restrict__ cur,
                           int* __restrict__ col, int e)
{
    int i = blockIdx.x * 256 + threadIdx.x;
    if (i < e) {
        int d = dst[i];
        int pos = atomicAdd(&cur[d], 1);
        col[rp[d] + pos] = src[i];
    }
}

// ---------------------------------------------------------------------------
// GAT projection + attention coefficients, fused.
// hp = x @ wT (fp32 accum); writes fp16-packed feature rows (hph) and
// per-(node,head) a_src/a_dst dots (as_, ad_). 32 nodes/block.
// ---------------------------------------------------------------------------
__global__ __launch_bounds__(256) void proj_attn(
    const float* __restrict__ x, const float* __restrict__ wT,
    const float* __restrict__ a_src, const float* __restrict__ a_dst,
    unsigned* __restrict__ hph, float* __restrict__ as_, float* __restrict__ ad_)
{
    __shared__ float xt[32][33];
    __shared__ float wt[32][128];
    __shared__ float ot[32][132];     // 132: 16B-aligned rows for float4 reads
    const int tid = threadIdx.x;
    const int tx = tid & 7;       // 8 node groups of 4
    const int ty = tid >> 3;      // 32 out groups of 4
    const int n0 = blockIdx.x * 32;
    float acc[4][4];
#pragma unroll
    for (int i = 0; i < 4; i++)
#pragma unroll
        for (int j = 0; j < 4; j++) acc[i][j] = 0.f;

    for (int k0 = 0; k0 < 128; k0 += 32) {
        __syncthreads();
#pragma unroll
        for (int i = 0; i < 4; i++) {
            int flat = tid + i * 256;
            int n = flat >> 5, k = flat & 31;
            xt[n][k] = x[(n0 + n) * HID + k0 + k];
        }
#pragma unroll
        for (int i = 0; i < 16; i++) {
            int flat = tid + i * 256;
            int kk = flat >> 7, g = flat & 127;
            wt[kk][g] = wT[(k0 + kk) * HID + g];
        }
        __syncthreads();
#pragma unroll 8
        for (int kk = 0; kk < 32; kk++) {
            float xv[4];
#pragma unroll
            for (int i = 0; i < 4; i++) xv[i] = xt[tx * 4 + i][kk];
            float4 wv = *(const float4*)&wt[kk][ty * 4];
#pragma unroll
            for (int i = 0; i < 4; i++) {
                acc[i][0] = fmaf(xv[i], wv.x, acc[i][0]);
                acc[i][1] = fmaf(xv[i], wv.y, acc[i][1]);
                acc[i][2] = fmaf(xv[i], wv.z, acc[i][2]);
                acc[i][3] = fmaf(xv[i], wv.w, acc[i][3]);
            }
        }
    }
    // epilogue: fp16-packed store + LDS tile for attention dots
#pragma unroll
    for (int i = 0; i < 4; i++) {
        int node = tx * 4 + i;
        ot[node][ty * 4 + 0] = acc[i][0];
        ot[node][ty * 4 + 1] = acc[i][1];
        ot[node][ty * 4 + 2] = acc[i][2];
        ot[node][ty * 4 + 3] = acc[i][3];
        uint2 pv;
        pv.x = hfpk(acc[i][0], acc[i][1]);
        pv.y = hfpk(acc[i][2], acc[i][3]);
        *(uint2*)&hph[(size_t)(n0 + node) * 64 + ty * 2] = pv;
    }
    __syncthreads();
    if (tid < 128) {
        int node = tid >> 2, head = tid & 3;
        const float* ar = a_src + head * 32;
        const float* br = a_dst + head * 32;
        float s = 0.f, d = 0.f;
#pragma unroll
        for (int j = 0; j < 32; j += 4) {
            float4 hv = *(const float4*)&ot[node][head * 32 + j];
            float4 av = *(const float4*)&ar[j];
            float4 bv = *(const float4*)&br[j];
            s += hv.x * av.x + hv.y * av.y + hv.z * av.z + hv.w * av.w;
            d += hv.x * bv.x + hv.y * bv.y + hv.z * bv.z + hv.w * bv.w;
        }
        as_[(n0 + node) * 4 + head] = s;
        ad_[(n0 + node) * 4 + head] = d;
    }
}

// ---------------------------------------------------------------------------
// GAT aggregation: one wave per dst node, CSR + implicit self-loop.
// Features gathered as fp16 pairs: lane owns channels (2*lane, 2*lane+1),
// one dword per edge per lane, coalesced. No max-pass (logits O(5), fp32 exp
// safe; shift is a mathematical no-op). CLF: classifier fused.
// ---------------------------------------------------------------------------
template <bool CLF>
__global__ __launch_bounds__(256) void gat_agg(
    const unsigned* __restrict__ hph, const float* __restrict__ as_,
    const float* __restrict__ ad_, const int* __restrict__ rp,
    const int* __restrict__ col, const float* __restrict__ bias,
    float* __restrict__ out, const float* __restrict__ cw,
    const float* __restrict__ cb, int n_nodes)
{
    __shared__ float exl[4][AGG_CAP][4];
    const int widx = threadIdx.x >> 6;
    const int lane = threadIdx.x & 63;
    const int n = blockIdx.x * 4 + widx;
    if (n >= n_nodes) return;

    const int e0 = rp[n], e1 = rp[n + 1];
    const int deg = e1 - e0;
    float4 adv = *(const float4*)&ad_[n * 4];
    float4 asn = *(const float4*)&as_[n * 4];
    // self-loop exp
    float xs0 = __expf(lrelu02(asn.x + adv.x)), xs1 = __expf(lrelu02(asn.y + adv.y));
    float xs2 = __expf(lrelu02(asn.z + adv.z)), xs3 = __expf(lrelu02(asn.w + adv.w));

    // phase A: exp per edge (lane-strided), cache in LDS, accumulate denoms
    float d0 = 0.f, d1 = 0.f, d2 = 0.f, d3 = 0.f;
    for (int e = e0 + lane; e < e1; e += 64) {
        int s = col[e];
        float4 a = *(const float4*)&as_[s * 4];
        float x0 = __expf(lrelu02(a.x + adv.x));
        float x1 = __expf(lrelu02(a.y + adv.y));
        float x2 = __expf(lrelu02(a.z + adv.z));
        float x3 = __expf(lrelu02(a.w + adv.w));
        int idx = e - e0;
        if (idx < AGG_CAP) {
            exl[widx][idx][0] = x0; exl[widx][idx][1] = x1;
            exl[widx][idx][2] = x2; exl[widx][idx][3] = x3;
        }
        d0 += x0; d1 += x1; d2 += x2; d3 += x3;
    }
#pragma unroll
    for (int off = 32; off >= 1; off >>= 1) {
        d0 += __shfl_xor(d0, off, 64);
        d1 += __shfl_xor(d1, off, 64);
        d2 += __shfl_xor(d2, off, 64);
        d3 += __shfl_xor(d3, off, 64);
    }
    d0 += xs0; d1 += xs1; d2 += xs2; d3 += xs3;
    float i0 = frcp(d0 + 1e-16f), i1 = frcp(d1 + 1e-16f);
    float i2 = frcp(d2 + 1e-16f), i3 = frcp(d3 + 1e-16f);

    // phase B: lane owns channel pair (2*lane, 2*lane+1); head = lane>>4
    const int head = lane >> 4;
    float invh = (head == 0) ? i0 : (head == 1) ? i1 : (head == 2) ? i2 : i3;
    float exsh = (head == 0) ? xs0 : (head == 1) ? xs1 : (head == 2) ? xs2 : xs3;
    float adh  = (head == 0) ? adv.x : (head == 1) ? adv.y : (head == 2) ? adv.z : adv.w;

    float2 sv = h2f2(hph[(size_t)n * 64 + lane]);
    float acc0 = exsh * sv.x;
    float acc1 = exsh * sv.y;

    if (deg <= AGG_CAP) {
        int e = e0;
        for (; e + 4 <= e1; e += 4) {
            int s_[4]; float w_[4]; unsigned u_[4];
#pragma unroll
            for (int u = 0; u < 4; u++) {
                s_[u] = col[e + u];
                w_[u] = exl[widx][e + u - e0][head];
            }
#pragma unroll
            for (int u = 0; u < 4; u++)
                u_[u] = hph[(size_t)s_[u] * 64 + lane];
#pragma unroll
            for (int u = 0; u < 4; u++) {
                float2 f = h2f2(u_[u]);
                acc0 = fmaf(w_[u], f.x, acc0);
                acc1 = fmaf(w_[u], f.y, acc1);
            }
        }
        for (; e < e1; e++) {
            int s = col[e];
            float w = exl[widx][e - e0][head];
            float2 f = h2f2(hph[(size_t)s * 64 + lane]);
            acc0 = fmaf(w, f.x, acc0);
            acc1 = fmaf(w, f.y, acc1);
        }
    } else {
        for (int e = e0; e < e1; e++) {
            int s = col[e];
            int idx = e - e0;
            float w;
            if (idx < AGG_CAP) w = exl[widx][idx][head];
            else               w = __expf(lrelu02(as_[s * 4 + head] + adh));
            float2 f = h2f2(hph[(size_t)s * 64 + lane]);
            acc0 = fmaf(w, f.x, acc0);
            acc1 = fmaf(w, f.y, acc1);
        }
    }

    float2 b2 = *(const float2*)&bias[2 * lane];
    float o0 = eluf_(acc0 * invh + b2.x);
    float o1 = eluf_(acc1 * invh + b2.y);
    if (CLF) {
        float2 cwv = *(const float2*)&cw[2 * lane];
        float v = o0 * cwv.x + o1 * cwv.y;
#pragma unroll
        for (int off = 32; off >= 1; off >>= 1) v += __shfl_xor(v, off, 64);
        if (lane == 0) out[n] = sigmoidf_(v + cb[0]);
    } else {
        *(float2*)&out[(size_t)n * HID + 2 * lane] = make_float2(o0, o1);
    }
}

// ---------------------------------------------------------------------------
extern "C" void kernel_launch(void* const* d_in, const int* in_sizes, int n_in,
                              void* d_out, int out_size, void* d_ws, size_t ws_size,
                              hipStream_t stream)
{
    const float* x     = (const float*)d_in[0];
    const int*   ei    = (const int*)d_in[1];
    const float* w_ih  = (const float*)d_in[2];
    const float* w_hh  = (const float*)d_in[3];
    const float* b_ih  = (const float*)d_in[4];
    const float* b_hh  = (const float*)d_in[5];
    const float* g1w   = (const float*)d_in[6];
    const float* g1as  = (const float*)d_in[7];
    const float* g1ad  = (const float*)d_in[8];
    const float* g1b   = (const float*)d_in[9];
    const float* g2w   = (const float*)d_in[10];
    const float* g2as  = (const float*)d_in[11];
    const float* g2ad  = (const float*)d_in[12];
    const float* g2b   = (const float*)d_in[13];
    const float* cw    = (const float*)d_in[14];
    const float* cb    = (const float*)d_in[15];
    float* out = (float*)d_out;

    char* wsb = (char*)d_ws;
    size_t off = 0;
    auto alc = [&](size_t bytes) { size_t o = off; off += (bytes + 255) & ~(size_t)255; return o; };

    float*    bufA = (float*)(wsb + alc((size_t)NP * HID * 4));      // GRU h
    float*    bufC = (float*)(wsb + alc((size_t)NP * HID * 4));      // layer-1 out
    unsigned* hph  = (unsigned*)(wsb + alc((size_t)NP * 64 * 4));    // fp16-packed features
    float*    as_  = (float*)(wsb + alc((size_t)NP * 4 * 4));
    float*    ad_  = (float*)(wsb + alc((size_t)NP * 4 * 4));
    float*    g1T  = (float*)(wsb + alc((size_t)128 * 128 * 4));
    float*    g2T  = (float*)(wsb + alc((size_t)128 * 128 * 4));
    int*      rp   = (int*)(wsb + alc((size_t)(N_NODES + 1) * 4));
    int*      deg  = (int*)(wsb + alc((size_t)N_NODES * 4));
    int*      cur  = (int*)(wsb + alc((size_t)N_NODES * 4));
    int*      col  = (int*)(wsb + alc((size_t)NEDGE * 4));
    int*      bsum = (int*)(wsb + alc((size_t)256 * 4));

    const int* src = ei;
    const int* dst = ei + NEDGE;

    hipMemsetAsync(deg, 0, (size_t)N_NODES * 4, stream);
    hipMemsetAsync(cur, 0, (size_t)N_NODES * 4, stream);

    prep_weights<<<64, 256, 0, stream>>>(g1w, g2w, g1T, g2T);

    // CSR build (reused by both GAT layers)
    count_edges<<<NEDGE / 256, 256, 0, stream>>>(dst, deg, NEDGE);
    scan_block_sums<<<NB_SCAN, 256, 0, stream>>>(deg, bsum, N_NODES);
    scan_bsum<<<1, 256, 0, stream>>>(bsum, NB_SCAN);
    scan_final<<<NB_SCAN, 256, 0, stream>>>(deg, bsum, rp, N_NODES);
    fill_edges<<<NEDGE / 256, 256, 0, stream>>>(src, dst, rp, cur, col, NEDGE);

    // fused GRU (all 16 steps), bf16 MFMA, h -> bufA
    gru_fused<<<NP / 32, 512, 0, stream>>>(x, w_ih, w_hh, b_ih, b_hh, bufA);

    // GAT layer 1: bufA -> hph/as_/ad_ (proj+attn) -> bufC (agg+elu)
    proj_attn<<<NP / 32, 256, 0, stream>>>(bufA, g1T, g1as, g1ad, hph, as_, ad_);
    gat_agg<false><<<(N_NODES + 3) / 4, 256, 0, stream>>>(hph, as_, ad_, rp, col, g1b, bufC,
                                                          nullptr, nullptr, N_NODES);

    // GAT layer 2: bufC -> hph/as_/ad_; agg fused with classifier -> out
    proj_attn<<<NP / 32, 256, 0, stream>>>(bufC, g2T, g2as, g2ad, hph, as_, ad_);
    gat_agg<true><<<(N_NODES + 3) / 4, 256, 0, stream>>>(hph, as_, ad_, rp, col, g2b, out,
                                                         cw, cb, N_NODES);
}